// Round 4
// baseline (5282.005 us; speedup 1.0000x reference)
//
#include <hip/hip_runtime.h>
#include <hip/hip_bf16.h>

#define TC    2049
#define DI    512
#define NS    128
#define XPN   288   // DT_RANK + 2*N_STATE = 32 + 256

__device__ __forceinline__ float us2f(unsigned short u) {
    union { unsigned int i; float f; } v; v.i = ((unsigned int)u) << 16; return v.f;
}
__device__ __forceinline__ float sigm(float x) { return 1.f / (1.f + expf(-x)); }

// ---------------- dtype sniffing: bf16 inputs (flag=0) vs f32 inputs (flag=1) -----
__global__ void detect_kernel(const unsigned short* __restrict__ x, int* __restrict__ flag) {
    __shared__ int cnt;
    int tid = threadIdx.x;
    if (tid == 0) cnt = 0;
    __syncthreads();
    unsigned short u = x[tid];
    int e = (u >> 7) & 0xFF;
    int insane = (u != 0 && (e < 97 || e > 157)) ? 1 : 0;
    atomicAdd(&cnt, insane);
    __syncthreads();
    if (tid == 0) *flag = (cnt >= 64) ? 1 : 0;
}

// ---------------- widen all inputs to f32 in workspace ----------------
struct WD { const void* src; float* dst; int n; };
struct WDT { WD e[25]; };
__global__ __launch_bounds__(256) void widen_all_kernel(WDT tab, const int* __restrict__ flag) {
    WD d = tab.e[blockIdx.y];
    const int f = *flag;
    const int stride = gridDim.x * 256;
    int i = blockIdx.x * 256 + threadIdx.x;
    if (f) {
        const float* s = (const float*)d.src;
        for (; i < d.n; i += stride) d.dst[i] = s[i];
    } else {
        const unsigned short* s = (const unsigned short*)d.src;
        for (; i < d.n; i += stride) d.dst[i] = us2f(s[i]);
    }
}

// ---------------- f32 GEMM, optional bias + relu, batched over gridDim.z ----------------
__global__ __launch_bounds__(256) void gemm_kernel(
    const float* __restrict__ A, int lda, long long sA,
    const float* __restrict__ W, int N,
    const float* __restrict__ bias,
    float* __restrict__ C, int ldc, long long sC,
    int M, int K, int act)
{
    A += (size_t)blockIdx.z * sA;
    C += (size_t)blockIdx.z * sC;
    __shared__ float As[16][64];   // As[k][m]
    __shared__ float Bs[16][64];   // Bs[k][n]
    const int tid = threadIdx.x;
    const int bm = blockIdx.x * 64;
    const int bn = blockIdx.y * 64;
    const int tx = tid & 15, ty = tid >> 4;
    const int arow = tid >> 2, ak = (tid & 3) << 2;
    const int bk = tid >> 4, bn0 = (tid & 15) << 2;
    float acc[4][4] = {};
    for (int kt = 0; kt < K; kt += 16) {
        float4 av = make_float4(0.f, 0.f, 0.f, 0.f);
        int grow = bm + arow;
        if (grow < M) av = *(const float4*)(A + (size_t)grow * lda + kt + ak);
        float4 bv;
        int gn = bn + bn0;
        const float* wrow = W + (size_t)(kt + bk) * N;
        if (gn + 3 < N) {
            bv = *(const float4*)(wrow + gn);
        } else {
            bv.x = (gn     < N) ? wrow[gn]     : 0.f;
            bv.y = (gn + 1 < N) ? wrow[gn + 1] : 0.f;
            bv.z = (gn + 2 < N) ? wrow[gn + 2] : 0.f;
            bv.w = (gn + 3 < N) ? wrow[gn + 3] : 0.f;
        }
        __syncthreads();
        As[ak][arow]     = av.x;
        As[ak + 1][arow] = av.y;
        As[ak + 2][arow] = av.z;
        As[ak + 3][arow] = av.w;
        *(float4*)&Bs[bk][bn0] = bv;
        __syncthreads();
#pragma unroll
        for (int k = 0; k < 16; ++k) {
            float4 a = *(const float4*)&As[k][ty << 2];
            float4 b = *(const float4*)&Bs[k][tx << 2];
            acc[0][0] += a.x * b.x; acc[0][1] += a.x * b.y; acc[0][2] += a.x * b.z; acc[0][3] += a.x * b.w;
            acc[1][0] += a.y * b.x; acc[1][1] += a.y * b.y; acc[1][2] += a.y * b.z; acc[1][3] += a.y * b.w;
            acc[2][0] += a.z * b.x; acc[2][1] += a.z * b.y; acc[2][2] += a.z * b.z; acc[2][3] += a.z * b.w;
            acc[3][0] += a.w * b.x; acc[3][1] += a.w * b.y; acc[3][2] += a.w * b.z; acc[3][3] += a.w * b.w;
        }
    }
    int gn = bn + (tx << 2);
    float bvals[4] = {0.f, 0.f, 0.f, 0.f};
    if (bias) {
#pragma unroll
        for (int j = 0; j < 4; ++j) if (gn + j < N) bvals[j] = bias[gn + j];
    }
#pragma unroll
    for (int i = 0; i < 4; ++i) {
        int r = bm + (ty << 2) + i;
        if (r < M) {
            float* crow = C + (size_t)r * ldc;
#pragma unroll
            for (int j = 0; j < 4; ++j) {
                if (gn + j < N) {
                    float v = acc[i][j] + bvals[j];
                    if (act == 1) v = fmaxf(v, 0.f);
                    crow[gn + j] = v;
                }
            }
        }
    }
}

// ---------------- causal depthwise conv (K=4) + silu, batched 2 dirs ----------------
__global__ __launch_bounds__(256) void conv_silu_kernel(
    const float* __restrict__ xzbase, int ld, long long bstride,
    const float* __restrict__ conv_w, const float* __restrict__ conv_b,
    float* __restrict__ xs, int T, int rev_mode)
{
    int idx = blockIdx.x * 256 + threadIdx.x;
    if (idx >= 2 * T * DI) return;
    int half = idx / (T * DI);
    int rem = idx - half * T * DI;
    int t = rem >> 9, d = rem & 511;
    const float* xzp = xzbase + (rev_mode ? 0 : (size_t)half * bstride);
    int rev = rev_mode ? half : 0;
    float acc = conv_b[d];
#pragma unroll
    for (int k = 0; k < 4; ++k) {
        int tt = t - 3 + k;
        if (tt >= 0) {
            int g = rev ? (T - 1 - tt) : tt;
            acc += conv_w[d * 4 + k] * xzp[(size_t)g * ld + d];
        }
    }
    xs[idx] = acc * sigm(acc);
}

// ---------------- selective scan + fused dt-proj + fused gating (simple) ----------------
__global__ __launch_bounds__(64) void scan_simple_kernel(
    const float* __restrict__ xdbl, const float* __restrict__ xs,
    const float* __restrict__ xz,
    const float* __restrict__ A_log, const float* __restrict__ dt_w,
    const float* __restrict__ dt_b, const float* __restrict__ Dp,
    float* __restrict__ y, int T)
{
    const int half = blockIdx.x >> 9;
    const int d = blockIdx.x & 511;
    const int lane = threadIdx.x;
    xs   += (size_t)half * T * DI;
    y    += (size_t)half * T * DI;
    xdbl += (size_t)half * T * XPN;
    const float a0 = -expf(A_log[d * NS + lane]);
    const float a1 = -expf(A_log[d * NS + 64 + lane]);
    const float wv  = dt_w[(lane & 31) * DI + d];
    const float dtb = dt_b[d];
    const float Dv  = Dp[d];
    float h0 = 0.f, h1 = 0.f;
    for (int t = 0; t < T; ++t) {
        const float* row = xdbl + (size_t)t * XPN;
        float part = row[lane & 31] * wv;
        part += __shfl_xor(part, 1, 64);
        part += __shfl_xor(part, 2, 64);
        part += __shfl_xor(part, 4, 64);
        part += __shfl_xor(part, 8, 64);
        part += __shfl_xor(part, 16, 64);
        float pre = part + dtb;
        float dv = (pre > 20.f) ? pre : log1pf(expf(pre));
        float B0 = row[32 + lane],  B1 = row[96 + lane];
        float C0 = row[160 + lane], C1 = row[224 + lane];
        float xv = xs[(size_t)t * DI + d];
        float u = dv * xv;
        h0 = h0 * expf(dv * a0) + u * B0;
        h1 = h1 * expf(dv * a1) + u * B1;
        float p = h0 * C0 + h1 * C1;
#pragma unroll
        for (int off = 32; off > 0; off >>= 1) p += __shfl_down(p, off, 64);
        if (lane == 0) {
            int tg = half ? (T - 1 - t) : t;
            float z = xz[(size_t)tg * 1024 + 512 + d];
            y[(size_t)t * DI + d] = (p + xv * Dv) * (z * sigm(z));
        }
    }
}

// ---------------- row softmax + scatter into both cross sequences ----------------
__global__ __launch_bounds__(256) void softmax_scatter_kernel(
    const float* __restrict__ yo, float* __restrict__ seq, int T)
{
    __shared__ float sm[4];
    const int t = blockIdx.x, half = blockIdx.y, tid = threadIdx.x;
    const float* row = yo + (size_t)half * T * DI + (size_t)t * DI;
    float v0 = row[tid], v1 = row[tid + 256];
    float m = fmaxf(v0, v1);
#pragma unroll
    for (int o = 32; o > 0; o >>= 1) m = fmaxf(m, __shfl_xor(m, o, 64));
    if ((tid & 63) == 0) sm[tid >> 6] = m;
    __syncthreads();
    m = fmaxf(fmaxf(sm[0], sm[1]), fmaxf(sm[2], sm[3]));
    __syncthreads();
    float e0 = expf(v0 - m), e1 = expf(v1 - m);
    float s = e0 + e1;
#pragma unroll
    for (int o = 32; o > 0; o >>= 1) s += __shfl_xor(s, o, 64);
    if ((tid & 63) == 0) sm[tid >> 6] = s;
    __syncthreads();
    s = sm[0] + sm[1] + sm[2] + sm[3];
    float inv = 1.f / s;
    e0 *= inv; e1 *= inv;
    float* seq_fi = seq;
    float* seq_if = seq + (size_t)TC * 1024;
    if (half == 0) {
        float* d1 = seq_fi + (size_t)t * 1024;
        float* d2 = seq_if + (size_t)t * 1024 + 512;
        d1[tid] = e0; d1[tid + 256] = e1;
        d2[tid] = e0; d2[tid + 256] = e1;
    } else {
        int tg = T - 1 - t;
        float* d1 = seq_fi + (size_t)tg * 1024 + 512;
        float* d2 = seq_if + (size_t)tg * 1024;
        d1[tid] = e0; d1[tid + 256] = e1;
        d2[tid] = e0; d2[tid + 256] = e1;
    }
}

// ---------------- cls-token rows of the two sequences ----------------
__global__ __launch_bounds__(256) void cls_rows_kernel(
    const float* __restrict__ cls1, const float* __restrict__ cls2,
    float* __restrict__ seq)
{
    int i = blockIdx.x * 256 + threadIdx.x;   // 0..2047
    if (i < 1024)
        seq[(size_t)(TC - 1) * 1024 + i] = cls1[i];
    else
        seq[(size_t)TC * 1024 + (size_t)(TC - 1) * 1024 + (i - 1024)] = cls2[i - 1024];
}

// ---------------- cross scan: fused dt-proj, last-step readout + gating ----------------
__global__ __launch_bounds__(64) void scan_cross_kernel(
    const float* __restrict__ xdbl, const float* __restrict__ xs,
    const float* __restrict__ xz,
    const float* __restrict__ A_log, const float* __restrict__ dt_w,
    const float* __restrict__ dt_b, const float* __restrict__ Dp,
    float* __restrict__ ylast, int T)
{
    const int half = blockIdx.x >> 9;
    const int d = blockIdx.x & 511;
    const int lane = threadIdx.x;
    xs   += (size_t)half * T * DI;
    xdbl += (size_t)half * T * XPN;
    xz   += (size_t)half * T * 1024;
    const float a0 = -expf(A_log[d * NS + lane]);
    const float a1 = -expf(A_log[d * NS + 64 + lane]);
    const float wv  = dt_w[(lane & 31) * DI + d];
    const float dtb = dt_b[d];
    const float Dv  = Dp[d];
    float h0 = 0.f, h1 = 0.f;
    for (int t = 0; t < T; ++t) {
        const float* row = xdbl + (size_t)t * XPN;
        float part = row[lane & 31] * wv;
        part += __shfl_xor(part, 1, 64);
        part += __shfl_xor(part, 2, 64);
        part += __shfl_xor(part, 4, 64);
        part += __shfl_xor(part, 8, 64);
        part += __shfl_xor(part, 16, 64);
        float pre = part + dtb;
        float dv = (pre > 20.f) ? pre : log1pf(expf(pre));
        float B0 = row[32 + lane], B1 = row[96 + lane];
        float xv = xs[(size_t)t * DI + d];
        float u = dv * xv;
        h0 = h0 * expf(dv * a0) + u * B0;
        h1 = h1 * expf(dv * a1) + u * B1;
    }
    const float* xl = xdbl + (size_t)(T - 1) * XPN;
    float p = h0 * xl[160 + lane] + h1 * xl[224 + lane];
#pragma unroll
    for (int off = 32; off > 0; off >>= 1) p += __shfl_down(p, off, 64);
    if (lane == 0) {
        float xlast = xs[(size_t)(T - 1) * DI + d];
        float zl = xz[(size_t)(T - 1) * 1024 + 512 + d];
        ylast[half * DI + d] = (p + xlast * Dv) * (zl * sigm(zl));
    }
}

// ---------------- vec [512] @ out_w [512,512] -> [512] ----------------
__global__ __launch_bounds__(256) void vecmat_kernel(
    const float* __restrict__ ylast, const float* __restrict__ Wout,
    float* __restrict__ olast)
{
    int half = blockIdx.y;
    int j = blockIdx.x * 256 + threadIdx.x;
    const float* v = ylast + half * DI;
    float acc = 0.f;
    for (int k = 0; k < DI; ++k) acc += v[k] * Wout[k * DI + j];
    olast[half * DI + j] = acc;
}

// ---------------- final classifier -> f32 [2] (reference output dtype) ----------------
__global__ __launch_bounds__(256) void final_kernel(
    const float* __restrict__ ol, const float* __restrict__ cw,
    const float* __restrict__ cb, float* __restrict__ out)
{
    __shared__ float s0[4], s1[4];
    int tid = threadIdx.x;
    float a0 = 0.f, a1 = 0.f;
    for (int j = tid; j < 1024; j += 256) {
        float v = ol[j];
        a0 += v * cw[2 * j];
        a1 += v * cw[2 * j + 1];
    }
#pragma unroll
    for (int o = 32; o > 0; o >>= 1) { a0 += __shfl_xor(a0, o, 64); a1 += __shfl_xor(a1, o, 64); }
    if ((tid & 63) == 0) { s0[tid >> 6] = a0; s1[tid >> 6] = a1; }
    __syncthreads();
    if (tid == 0) {
        out[0] = s0[0] + s0[1] + s0[2] + s0[3] + cb[0];
        out[1] = s1[0] + s1[1] + s1[2] + s1[3] + cb[1];
    }
}

extern "C" void kernel_launch(void* const* d_in, const int* in_sizes, int n_in,
                              void* d_out, int out_size, void* d_ws, size_t ws_size,
                              hipStream_t stream)
{
    float* out = (float*)d_out;
    float* ws = (float*)d_ws;

    // ---- input-order resolution via in_sizes ----
    // dict order (setup_inputs): idx6 = cls_b (2 elems). signature order: idx6 = m_conv_w (2048).
    // logical slots (dict order): 0:x 1:feat_w 2:feat_b 3:cls1 4:cls2 5:cls_w 6:cls_b
    //                             7..15: m_*  16..24: c_*
    static const int sig_map[25] = {0,1,2,3,4,23,24,5,6,7,8,9,10,11,12,13,
                                    14,15,16,17,18,19,20,21,22};
    int idx[25];
    bool dict_order = (n_in >= 7 && in_sizes[6] == 2);
    for (int i = 0; i < 25; ++i) idx[i] = dict_order ? i : sig_map[i];

    // ---- tight aliased workspace layout (f32 elements), total ~72 MB ----
    const size_t A0 = 0;                       // XF -> yo -> XSC   (2,098,176)
    const size_t B0 = 2098176;                 // F -> XDC          (1,180,224)
    const size_t C0 = 3278400;                 // XZS / XZC         (2,097,152+)
    const size_t D0 = 5375552;                 // XS                (2,097,152)
    const size_t E0 = 7472704;                 // XDBL              (1,179,648)
    const size_t F0 = 8652352;                 // YS                (2,097,152)
    const size_t G0 = 10749504;                // SEQ               (4,196,352)
    const size_t YL0 = 14945856;               // 1024
    const size_t OL0 = 14946880;               // 1024
    size_t o = 14947904;
    const size_t P_FEATW = o; o += 524288;
    const size_t P_FEATB = o; o += 512;
    const size_t P_CLS1  = o; o += 1024;
    const size_t P_CLS2  = o; o += 1024;
    const size_t P_CLSW  = o; o += 2048;
    const size_t P_CLSB  = o; o += 4;
    const size_t P_MINW  = o; o += 524288;
    const size_t P_MCW   = o; o += 2048;
    const size_t P_MCB   = o; o += 512;
    const size_t P_MXP   = o; o += 147456;
    const size_t P_MDTW  = o; o += 16384;
    const size_t P_MDTB  = o; o += 512;
    const size_t P_MAL   = o; o += 65536;
    const size_t P_MD    = o; o += 512;
    const size_t P_MOW   = o; o += 262144;
    const size_t P_CINW  = o; o += 1048576;
    const size_t P_CCW   = o; o += 2048;
    const size_t P_CCB   = o; o += 512;
    const size_t P_CXP   = o; o += 147456;
    const size_t P_CDTW  = o; o += 16384;
    const size_t P_CDTB  = o; o += 512;
    const size_t P_CAL   = o; o += 65536;
    const size_t P_CD    = o; o += 512;
    const size_t P_COW   = o; o += 262144;
    const size_t OFF_FLAG = o;                 // 1 int

    int* flagp = (int*)(ws + OFF_FLAG);

    // 0) detect input dtype (bf16 vs f32) from x's bit patterns
    detect_kernel<<<1, 256, 0, stream>>>((const unsigned short*)d_in[idx[0]], flagp);

    // 1) widen all 25 inputs to f32
    WDT tab;
    const int ns[25] = {2097152, 524288, 512, 1024, 1024, 2048, 2,
                        524288, 2048, 512, 147456, 16384, 512, 65536, 512, 262144,
                        1048576, 2048, 512, 147456, 16384, 512, 65536, 512, 262144};
    float* dsts[25] = {
        ws + A0, ws + P_FEATW, ws + P_FEATB, ws + P_CLS1, ws + P_CLS2,
        ws + P_CLSW, ws + P_CLSB,
        ws + P_MINW, ws + P_MCW, ws + P_MCB, ws + P_MXP, ws + P_MDTW, ws + P_MDTB,
        ws + P_MAL, ws + P_MD, ws + P_MOW,
        ws + P_CINW, ws + P_CCW, ws + P_CCB, ws + P_CXP, ws + P_CDTW, ws + P_CDTB,
        ws + P_CAL, ws + P_CD, ws + P_COW};
    for (int i = 0; i < 25; ++i) {
        tab.e[i].src = d_in[idx[i]];
        tab.e[i].dst = dsts[i];
        tab.e[i].n = ns[i];
    }
    widen_all_kernel<<<dim3(128, 25), 256, 0, stream>>>(tab, flagp);

    // 2) f = relu(x @ feat_w + feat_b)        A -> B
    gemm_kernel<<<dim3(32, 8, 1), 256, 0, stream>>>(ws + A0, 1024, 0, ws + P_FEATW, 512,
                                                    ws + P_FEATB, ws + B0, 512, 0, 2048, 1024, 1);
    // 3) xz = f @ m_in_w                      B -> C
    gemm_kernel<<<dim3(32, 16, 1), 256, 0, stream>>>(ws + B0, 512, 0, ws + P_MINW, 1024, nullptr,
                                                     ws + C0, 1024, 0, 2048, 512, 0);
    // 4) conv+silu, both directions           C -> D
    conv_silu_kernel<<<8192, 256, 0, stream>>>(ws + C0, 1024, 0, ws + P_MCW, ws + P_MCB,
                                               ws + D0, 2048, 1);
    // 5) x_dbl = xs @ m_xproj_w               D -> E
    gemm_kernel<<<dim3(32, 5, 2), 256, 0, stream>>>(ws + D0, 512, 2048LL * 512, ws + P_MXP, 288,
                                                    nullptr, ws + E0, 288, 2048LL * 288,
                                                    2048, 512, 0);
    // 6) scans (fused dt + gating)            E,D,C -> F
    scan_simple_kernel<<<1024, 64, 0, stream>>>(ws + E0, ws + D0, ws + C0,
                                                ws + P_MAL, ws + P_MDTW, ws + P_MDTB, ws + P_MD,
                                                ws + F0, 2048);
    // 7) yo = y @ m_out_w                     F -> A (yo)
    gemm_kernel<<<dim3(32, 8, 2), 256, 0, stream>>>(ws + F0, 512, 2048LL * 512, ws + P_MOW, 512,
                                                    nullptr, ws + A0, 512, 2048LL * 512,
                                                    2048, 512, 0);
    // 8) cls-token rows into SEQ              P -> G
    cls_rows_kernel<<<8, 256, 0, stream>>>(ws + P_CLS1, ws + P_CLS2, ws + G0);
    // 9) softmax + scatter                    A -> G
    softmax_scatter_kernel<<<dim3(2048, 2), 256, 0, stream>>>(ws + A0, ws + G0, 2048);
    // 10) cross in-proj                       G -> C (XZC spans C..E)
    gemm_kernel<<<dim3(33, 16, 2), 256, 0, stream>>>(ws + G0, 1024, 2049LL * 1024, ws + P_CINW,
                                                     1024, nullptr, ws + C0, 1024, 2049LL * 1024,
                                                     2049, 1024, 0);
    // 11) cross conv+silu                     C -> A (XSC)
    conv_silu_kernel<<<8196, 256, 0, stream>>>(ws + C0, 1024, 2049LL * 1024, ws + P_CCW,
                                               ws + P_CCB, ws + A0, 2049, 0);
    // 12) cross x_dbl                         A -> B (XDC)
    gemm_kernel<<<dim3(33, 5, 2), 256, 0, stream>>>(ws + A0, 512, 2049LL * 512, ws + P_CXP, 288,
                                                    nullptr, ws + B0, 288, 2049LL * 288,
                                                    2049, 512, 0);
    // 13) cross scans (fused dt, last-step readout + gating)  B,A,C -> YL
    scan_cross_kernel<<<1024, 64, 0, stream>>>(ws + B0, ws + A0, ws + C0,
                                               ws + P_CAL, ws + P_CDTW, ws + P_CDTB, ws + P_CD,
                                               ws + YL0, 2049);
    // 14) out-projection of last rows         YL -> OL
    vecmat_kernel<<<dim3(2, 2), 256, 0, stream>>>(ws + YL0, ws + P_COW, ws + OL0);
    // 15) classifier                          OL -> out (f32)
    final_kernel<<<1, 256, 0, stream>>>(ws + OL0, ws + P_CLSW, ws + P_CLSB, out);
}

// Round 6
// 1119.312 us; speedup vs baseline: 4.7190x; 4.7190x over previous
//
#include <hip/hip_runtime.h>
#include <hip/hip_bf16.h>

#define TC    2049
#define DI    512
#define NS    128
#define XPN   288   // DT_RANK + 2*N_STATE = 32 + 256

__device__ __forceinline__ float us2f(unsigned short u) {
    union { unsigned int i; float f; } v; v.i = ((unsigned int)u) << 16; return v.f;
}
__device__ __forceinline__ float sigm(float x) { return 1.f / (1.f + expf(-x)); }

// ---------------- dtype sniffing: bf16 inputs (flag=0) vs f32 inputs (flag=1) -----
__global__ void detect_kernel(const unsigned short* __restrict__ x, int* __restrict__ flag) {
    __shared__ int cnt;
    int tid = threadIdx.x;
    if (tid == 0) cnt = 0;
    __syncthreads();
    unsigned short u = x[tid];
    int e = (u >> 7) & 0xFF;
    int insane = (u != 0 && (e < 97 || e > 157)) ? 1 : 0;
    atomicAdd(&cnt, insane);
    __syncthreads();
    if (tid == 0) *flag = (cnt >= 64) ? 1 : 0;
}

// ---------------- widen all inputs to f32 in workspace ----------------
struct WD { const void* src; float* dst; int n; };
struct WDT { WD e[25]; };
__global__ __launch_bounds__(256) void widen_all_kernel(WDT tab, const int* __restrict__ flag) {
    WD d = tab.e[blockIdx.y];
    const int f = *flag;
    const int stride = gridDim.x * 256;
    int i = blockIdx.x * 256 + threadIdx.x;
    if (f) {
        const float* s = (const float*)d.src;
        for (; i < d.n; i += stride) d.dst[i] = s[i];
    } else {
        const unsigned short* s = (const unsigned short*)d.src;
        for (; i < d.n; i += stride) d.dst[i] = us2f(s[i]);
    }
}

// ---------------- f32 GEMM, optional bias + relu, batched over gridDim.z ----------------
__global__ __launch_bounds__(256) void gemm_kernel(
    const float* __restrict__ A, int lda, long long sA,
    const float* __restrict__ W, int N,
    const float* __restrict__ bias,
    float* __restrict__ C, int ldc, long long sC,
    int M, int K, int act)
{
    A += (size_t)blockIdx.z * sA;
    C += (size_t)blockIdx.z * sC;
    __shared__ float As[16][64];   // As[k][m]
    __shared__ float Bs[16][64];   // Bs[k][n]
    const int tid = threadIdx.x;
    const int bm = blockIdx.x * 64;
    const int bn = blockIdx.y * 64;
    const int tx = tid & 15, ty = tid >> 4;
    const int arow = tid >> 2, ak = (tid & 3) << 2;
    const int bk = tid >> 4, bn0 = (tid & 15) << 2;
    float acc[4][4] = {};
    for (int kt = 0; kt < K; kt += 16) {
        float4 av = make_float4(0.f, 0.f, 0.f, 0.f);
        int grow = bm + arow;
        if (grow < M) av = *(const float4*)(A + (size_t)grow * lda + kt + ak);
        float4 bv;
        int gn = bn + bn0;
        const float* wrow = W + (size_t)(kt + bk) * N;
        if (gn + 3 < N) {
            bv = *(const float4*)(wrow + gn);
        } else {
            bv.x = (gn     < N) ? wrow[gn]     : 0.f;
            bv.y = (gn + 1 < N) ? wrow[gn + 1] : 0.f;
            bv.z = (gn + 2 < N) ? wrow[gn + 2] : 0.f;
            bv.w = (gn + 3 < N) ? wrow[gn + 3] : 0.f;
        }
        __syncthreads();
        As[ak][arow]     = av.x;
        As[ak + 1][arow] = av.y;
        As[ak + 2][arow] = av.z;
        As[ak + 3][arow] = av.w;
        *(float4*)&Bs[bk][bn0] = bv;
        __syncthreads();
#pragma unroll
        for (int k = 0; k < 16; ++k) {
            float4 a = *(const float4*)&As[k][ty << 2];
            float4 b = *(const float4*)&Bs[k][tx << 2];
            acc[0][0] += a.x * b.x; acc[0][1] += a.x * b.y; acc[0][2] += a.x * b.z; acc[0][3] += a.x * b.w;
            acc[1][0] += a.y * b.x; acc[1][1] += a.y * b.y; acc[1][2] += a.y * b.z; acc[1][3] += a.y * b.w;
            acc[2][0] += a.z * b.x; acc[2][1] += a.z * b.y; acc[2][2] += a.z * b.z; acc[2][3] += a.z * b.w;
            acc[3][0] += a.w * b.x; acc[3][1] += a.w * b.y; acc[3][2] += a.w * b.z; acc[3][3] += a.w * b.w;
        }
    }
    int gn = bn + (tx << 2);
    float bvals[4] = {0.f, 0.f, 0.f, 0.f};
    if (bias) {
#pragma unroll
        for (int j = 0; j < 4; ++j) if (gn + j < N) bvals[j] = bias[gn + j];
    }
#pragma unroll
    for (int i = 0; i < 4; ++i) {
        int r = bm + (ty << 2) + i;
        if (r < M) {
            float* crow = C + (size_t)r * ldc;
#pragma unroll
            for (int j = 0; j < 4; ++j) {
                if (gn + j < N) {
                    float v = acc[i][j] + bvals[j];
                    if (act == 1) v = fmaxf(v, 0.f);
                    crow[gn + j] = v;
                }
            }
        }
    }
}

// ---------------- causal depthwise conv (K=4) + silu, batched 2 dirs ----------------
__global__ __launch_bounds__(256) void conv_silu_kernel(
    const float* __restrict__ xzbase, int ld, long long bstride,
    const float* __restrict__ conv_w, const float* __restrict__ conv_b,
    float* __restrict__ xs, int T, int rev_mode)
{
    int idx = blockIdx.x * 256 + threadIdx.x;
    if (idx >= 2 * T * DI) return;
    int half = idx / (T * DI);
    int rem = idx - half * T * DI;
    int t = rem >> 9, d = rem & 511;
    const float* xzp = xzbase + (rev_mode ? 0 : (size_t)half * bstride);
    int rev = rev_mode ? half : 0;
    float acc = conv_b[d];
#pragma unroll
    for (int k = 0; k < 4; ++k) {
        int tt = t - 3 + k;
        if (tt >= 0) {
            int g = rev ? (T - 1 - tt) : tt;
            acc += conv_w[d * 4 + k] * xzp[(size_t)g * ld + d];
        }
    }
    xs[idx] = acc * sigm(acc);
}

// ---------------- dt projection (K=32) + softplus ----------------
__global__ __launch_bounds__(256) void dt_kernel(
    const float* __restrict__ xdbl, const float* __restrict__ dt_w,
    const float* __restrict__ dt_b, float* __restrict__ dtout, int T)
{
    int idx = blockIdx.x * 256 + threadIdx.x;
    if (idx >= 2 * T * DI) return;
    int half = idx / (T * DI);
    int rem = idx - half * T * DI;
    int t = rem >> 9, j = rem & 511;
    const float* a = xdbl + (size_t)half * T * XPN + (size_t)t * XPN;
    float acc = dt_b[j];
#pragma unroll
    for (int k = 0; k < 32; ++k) acc += a[k] * dt_w[k * DI + j];
    dtout[idx] = (acc > 20.f) ? acc : log1pf(expf(acc));
}

// ---------------- chunked scan pass 1: per-chunk decay product + zero-seeded partial ----
__global__ __launch_bounds__(64) void scan_part1_kernel(
    const float* __restrict__ dt, const float* __restrict__ xdbl,
    const float* __restrict__ xs, const float* __restrict__ A_log,
    float* __restrict__ P, float* __restrict__ H, int T, int NC, int LC)
{
    int b = blockIdx.x;
    int c = b % NC;
    int hd = b / NC;
    int half = hd >> 9, d = hd & 511;
    int lane = threadIdx.x;
    dt   += (size_t)half * T * DI;
    xs   += (size_t)half * T * DI;
    xdbl += (size_t)half * T * XPN;
    const float a0 = -expf(A_log[d * NS + lane]);
    const float a1 = -expf(A_log[d * NS + 64 + lane]);
    float P0 = 1.f, P1 = 1.f, h0 = 0.f, h1 = 0.f;
    int t0 = c * LC, t1 = min(T, t0 + LC);
    for (int t = t0; t < t1; ++t) {
        const float* row = xdbl + (size_t)t * XPN;
        float dv = dt[(size_t)t * DI + d];
        float xv = xs[(size_t)t * DI + d];
        float B0 = row[32 + lane], B1 = row[96 + lane];
        float e0 = expf(dv * a0), e1 = expf(dv * a1);
        float u = dv * xv;
        h0 = h0 * e0 + u * B0;
        h1 = h1 * e1 + u * B1;
        P0 *= e0; P1 *= e1;
    }
    size_t base = ((size_t)hd * NC + c) * 128;
    P[base + lane] = P0;       P[base + 64 + lane] = P1;
    H[base + lane] = h0;       H[base + 64 + lane] = h1;
}

// ---------------- chunked scan pass 2: serial combine across chunks ----------------
__global__ __launch_bounds__(128) void scan_combine_kernel(
    float* __restrict__ P, const float* __restrict__ H,
    float* __restrict__ Hfinal, int NC)
{
    int hd = blockIdx.x;
    int n = threadIdx.x;
    size_t base = (size_t)hd * NC * 128 + n;
    float h = 0.f;
    for (int c = 0; c < NC; ++c) {
        size_t off = base + (size_t)c * 128;
        float p = P[off];
        float hh = H[off];
        P[off] = h;                // h_start for chunk c (exclusive prefix)
        h = p * h + hh;
    }
    if (Hfinal) Hfinal[(size_t)hd * 128 + n] = h;
}

// ---------------- chunked scan pass 3: replay with seed, emit gated y (simple) --------
__global__ __launch_bounds__(64) void scan_emit_kernel(
    const float* __restrict__ dt, const float* __restrict__ xdbl,
    const float* __restrict__ xs, const float* __restrict__ xz,
    const float* __restrict__ A_log, const float* __restrict__ Hstart,
    const float* __restrict__ Dp, float* __restrict__ y, int T, int NC, int LC)
{
    int b = blockIdx.x;
    int c = b % NC;
    int hd = b / NC;
    int half = hd >> 9, d = hd & 511;
    int lane = threadIdx.x;
    dt   += (size_t)half * T * DI;
    xs   += (size_t)half * T * DI;
    xdbl += (size_t)half * T * XPN;
    y    += (size_t)half * T * DI;
    const float a0 = -expf(A_log[d * NS + lane]);
    const float a1 = -expf(A_log[d * NS + 64 + lane]);
    const float Dv = Dp[d];
    size_t base = ((size_t)hd * NC + c) * 128;
    float h0 = Hstart[base + lane];
    float h1 = Hstart[base + 64 + lane];
    int t0 = c * LC, t1 = min(T, t0 + LC);
    for (int t = t0; t < t1; ++t) {
        const float* row = xdbl + (size_t)t * XPN;
        float dv = dt[(size_t)t * DI + d];
        float xv = xs[(size_t)t * DI + d];
        float B0 = row[32 + lane],  B1 = row[96 + lane];
        float C0 = row[160 + lane], C1 = row[224 + lane];
        float e0 = expf(dv * a0), e1 = expf(dv * a1);
        float u = dv * xv;
        h0 = h0 * e0 + u * B0;
        h1 = h1 * e1 + u * B1;
        float p = h0 * C0 + h1 * C1;
#pragma unroll
        for (int off = 32; off > 0; off >>= 1) p += __shfl_down(p, off, 64);
        if (lane == 0) {
            int tg = half ? (T - 1 - t) : t;
            float z = xz[(size_t)tg * 1024 + 512 + d];
            y[(size_t)t * DI + d] = (p + xv * Dv) * (z * sigm(z));
        }
    }
}

// ---------------- cross: last-step readout from final state + gating ----------------
__global__ __launch_bounds__(64) void cross_readout_kernel(
    const float* __restrict__ Hfinal, const float* __restrict__ xdbl,
    const float* __restrict__ xs, const float* __restrict__ xz,
    const float* __restrict__ Dp, float* __restrict__ ylast, int T)
{
    int hd = blockIdx.x;
    int half = hd >> 9, d = hd & 511;
    int lane = threadIdx.x;
    xdbl += (size_t)half * T * XPN;
    xs   += (size_t)half * T * DI;
    xz   += (size_t)half * T * 1024;
    float h0 = Hfinal[(size_t)hd * 128 + lane];
    float h1 = Hfinal[(size_t)hd * 128 + 64 + lane];
    const float* xl = xdbl + (size_t)(T - 1) * XPN;
    float p = h0 * xl[160 + lane] + h1 * xl[224 + lane];
#pragma unroll
    for (int off = 32; off > 0; off >>= 1) p += __shfl_down(p, off, 64);
    if (lane == 0) {
        float xlast = xs[(size_t)(T - 1) * DI + d];
        float zl = xz[(size_t)(T - 1) * 1024 + 512 + d];
        ylast[half * DI + d] = (p + xlast * Dp[d]) * (zl * sigm(zl));
    }
}

// ---------------- row softmax + scatter into both cross sequences ----------------
__global__ __launch_bounds__(256) void softmax_scatter_kernel(
    const float* __restrict__ yo, float* __restrict__ seq, int T)
{
    __shared__ float sm[4];
    const int t = blockIdx.x, half = blockIdx.y, tid = threadIdx.x;
    const float* row = yo + (size_t)half * T * DI + (size_t)t * DI;
    float v0 = row[tid], v1 = row[tid + 256];
    float m = fmaxf(v0, v1);
#pragma unroll
    for (int o = 32; o > 0; o >>= 1) m = fmaxf(m, __shfl_xor(m, o, 64));
    if ((tid & 63) == 0) sm[tid >> 6] = m;
    __syncthreads();
    m = fmaxf(fmaxf(sm[0], sm[1]), fmaxf(sm[2], sm[3]));
    __syncthreads();
    float e0 = expf(v0 - m), e1 = expf(v1 - m);
    float s = e0 + e1;
#pragma unroll
    for (int o = 32; o > 0; o >>= 1) s += __shfl_xor(s, o, 64);
    if ((tid & 63) == 0) sm[tid >> 6] = s;
    __syncthreads();
    s = sm[0] + sm[1] + sm[2] + sm[3];
    float inv = 1.f / s;
    e0 *= inv; e1 *= inv;
    float* seq_fi = seq;
    float* seq_if = seq + (size_t)TC * 1024;
    if (half == 0) {
        float* d1 = seq_fi + (size_t)t * 1024;
        float* d2 = seq_if + (size_t)t * 1024 + 512;
        d1[tid] = e0; d1[tid + 256] = e1;
        d2[tid] = e0; d2[tid + 256] = e1;
    } else {
        int tg = T - 1 - t;
        float* d1 = seq_fi + (size_t)tg * 1024 + 512;
        float* d2 = seq_if + (size_t)tg * 1024;
        d1[tid] = e0; d1[tid + 256] = e1;
        d2[tid] = e0; d2[tid + 256] = e1;
    }
}

// ---------------- cls-token rows of the two sequences ----------------
__global__ __launch_bounds__(256) void cls_rows_kernel(
    const float* __restrict__ cls1, const float* __restrict__ cls2,
    float* __restrict__ seq)
{
    int i = blockIdx.x * 256 + threadIdx.x;   // 0..2047
    if (i < 1024)
        seq[(size_t)(TC - 1) * 1024 + i] = cls1[i];
    else
        seq[(size_t)TC * 1024 + (size_t)(TC - 1) * 1024 + (i - 1024)] = cls2[i - 1024];
}

// ---------------- vec [512] @ out_w [512,512] -> [512] ----------------
__global__ __launch_bounds__(256) void vecmat_kernel(
    const float* __restrict__ ylast, const float* __restrict__ Wout,
    float* __restrict__ olast)
{
    int half = blockIdx.y;
    int j = blockIdx.x * 256 + threadIdx.x;
    const float* v = ylast + half * DI;
    float acc = 0.f;
    for (int k = 0; k < DI; ++k) acc += v[k] * Wout[k * DI + j];
    olast[half * DI + j] = acc;
}

// ---------------- final classifier -> f32 [2] ----------------
__global__ __launch_bounds__(256) void final_kernel(
    const float* __restrict__ ol, const float* __restrict__ cw,
    const float* __restrict__ cb, float* __restrict__ out)
{
    __shared__ float s0[4], s1[4];
    int tid = threadIdx.x;
    float a0 = 0.f, a1 = 0.f;
    for (int j = tid; j < 1024; j += 256) {
        float v = ol[j];
        a0 += v * cw[2 * j];
        a1 += v * cw[2 * j + 1];
    }
#pragma unroll
    for (int o = 32; o > 0; o >>= 1) { a0 += __shfl_xor(a0, o, 64); a1 += __shfl_xor(a1, o, 64); }
    if ((tid & 63) == 0) { s0[tid >> 6] = a0; s1[tid >> 6] = a1; }
    __syncthreads();
    if (tid == 0) {
        out[0] = s0[0] + s0[1] + s0[2] + s0[3] + cb[0];
        out[1] = s1[0] + s1[1] + s1[2] + s1[3] + cb[1];
    }
}

extern "C" void kernel_launch(void* const* d_in, const int* in_sizes, int n_in,
                              void* d_out, int out_size, void* d_ws, size_t ws_size,
                              hipStream_t stream)
{
    float* out = (float*)d_out;
    float* ws = (float*)d_ws;

    // ---- input-order resolution via in_sizes (dict vs signature order) ----
    static const int sig_map[25] = {0,1,2,3,4,23,24,5,6,7,8,9,10,11,12,13,
                                    14,15,16,17,18,19,20,21,22};
    int idx[25];
    bool dict_order = (n_in >= 7 && in_sizes[6] == 2);
    for (int i = 0; i < 25; ++i) idx[i] = dict_order ? i : sig_map[i];

    // ---- aliased workspace layout (f32 elements) ----
    // Phase 1 (simple mamba):
    //   A0: x(f32) -> dt_simple     B0: f     C0: XZS   D0: XS   E0: XDBL
    //   F0: YS    G0: P_S | H_S  (then SEQ after scan)
    // Phase 2 (cross mamba):
    //   A0: XSC   B0: XDC   C0..: XZC (spans C,D,+2048 of E)
    //   DT_C after XZC; P_C/H_C/HFIN over dead YS/SEQ tails.
    const size_t A0 = 0;         // 2,098,176
    const size_t B0 = 2098176;   // 1,180,224
    const size_t C0 = 3278400;   // 2,097,152 (XZC spans [C0, C0+4,196,352) = ..7,474,752)
    const size_t D0 = 5375552;   // 2,097,152
    const size_t E0 = 7472704;   // 1,179,648
    const size_t F0 = 8652352;   // 2,097,152
    const size_t G0 = 10749504;  // 4,196,352 (SEQ)
    const size_t YL0 = 14945856; // 1024
    const size_t OL0 = 14946880; // 1024
    // simple-scan scratch:
    const size_t DT_S = A0;                  // 2,097,152 (x dead after step 2)
    const size_t P_S  = G0;                  // 2,097,152 (SEQ not yet live)
    const size_t H_S  = G0 + 2097152;        // 2,097,152 (ends 14,943,808 < YL0)
    // cross-scan scratch (all after live XZC end = 7,474,752; YS/SEQ dead by then):
    const size_t DT_C = 7474752;             // 2,098,176 -> ends  9,572,928
    const size_t P_C  = 9572928;             // 2,228,224 -> ends 11,801,152
    const size_t H_C  = 11801152;            // 2,228,224 -> ends 14,029,376
    const size_t HFIN = 14029376;            //   131,072 -> ends 14,160,448 < YL0
    size_t o = 14947904;
    const size_t P_FEATW = o; o += 524288;
    const size_t P_FEATB = o; o += 512;
    const size_t P_CLS1  = o; o += 1024;
    const size_t P_CLS2  = o; o += 1024;
    const size_t P_CLSW  = o; o += 2048;
    const size_t P_CLSB  = o; o += 4;
    const size_t P_MINW  = o; o += 524288;
    const size_t P_MCW   = o; o += 2048;
    const size_t P_MCB   = o; o += 512;
    const size_t P_MXP   = o; o += 147456;
    const size_t P_MDTW  = o; o += 16384;
    const size_t P_MDTB  = o; o += 512;
    const size_t P_MAL   = o; o += 65536;
    const size_t P_MD    = o; o += 512;
    const size_t P_MOW   = o; o += 262144;
    const size_t P_CINW  = o; o += 1048576;
    const size_t P_CCW   = o; o += 2048;
    const size_t P_CCB   = o; o += 512;
    const size_t P_CXP   = o; o += 147456;
    const size_t P_CDTW  = o; o += 16384;
    const size_t P_CDTB  = o; o += 512;
    const size_t P_CAL   = o; o += 65536;
    const size_t P_CD    = o; o += 512;
    const size_t P_COW   = o; o += 262144;
    const size_t OFF_FLAG = o;               // 1 int

    int* flagp = (int*)(ws + OFF_FLAG);

    // 0) detect input dtype
    detect_kernel<<<1, 256, 0, stream>>>((const unsigned short*)d_in[idx[0]], flagp);

    // 1) widen all 25 inputs to f32
    WDT tab;
    const int ns[25] = {2097152, 524288, 512, 1024, 1024, 2048, 2,
                        524288, 2048, 512, 147456, 16384, 512, 65536, 512, 262144,
                        1048576, 2048, 512, 147456, 16384, 512, 65536, 512, 262144};
    float* dsts[25] = {
        ws + A0, ws + P_FEATW, ws + P_FEATB, ws + P_CLS1, ws + P_CLS2,
        ws + P_CLSW, ws + P_CLSB,
        ws + P_MINW, ws + P_MCW, ws + P_MCB, ws + P_MXP, ws + P_MDTW, ws + P_MDTB,
        ws + P_MAL, ws + P_MD, ws + P_MOW,
        ws + P_CINW, ws + P_CCW, ws + P_CCB, ws + P_CXP, ws + P_CDTW, ws + P_CDTB,
        ws + P_CAL, ws + P_CD, ws + P_COW};
    for (int i = 0; i < 25; ++i) {
        tab.e[i].src = d_in[idx[i]];
        tab.e[i].dst = dsts[i];
        tab.e[i].n = ns[i];
    }
    widen_all_kernel<<<dim3(128, 25), 256, 0, stream>>>(tab, flagp);

    // 2) f = relu(x @ feat_w + feat_b)        A -> B
    gemm_kernel<<<dim3(32, 8, 1), 256, 0, stream>>>(ws + A0, 1024, 0, ws + P_FEATW, 512,
                                                    ws + P_FEATB, ws + B0, 512, 0, 2048, 1024, 1);
    // 3) xz = f @ m_in_w                      B -> C
    gemm_kernel<<<dim3(32, 16, 1), 256, 0, stream>>>(ws + B0, 512, 0, ws + P_MINW, 1024, nullptr,
                                                     ws + C0, 1024, 0, 2048, 512, 0);
    // 4) conv+silu, both directions           C -> D
    conv_silu_kernel<<<8192, 256, 0, stream>>>(ws + C0, 1024, 0, ws + P_MCW, ws + P_MCB,
                                               ws + D0, 2048, 1);
    // 5) x_dbl = xs @ m_xproj_w               D -> E
    gemm_kernel<<<dim3(32, 5, 2), 256, 0, stream>>>(ws + D0, 512, 2048LL * 512, ws + P_MXP, 288,
                                                    nullptr, ws + E0, 288, 2048LL * 288,
                                                    2048, 512, 0);
    // 5b) dt = softplus(x_dbl[:, :32] @ dt_w + dt_b)   E -> DT_S (A)
    dt_kernel<<<8192, 256, 0, stream>>>(ws + E0, ws + P_MDTW, ws + P_MDTB, ws + DT_S, 2048);
    // 6) chunked scan: T=2048, 16 chunks x 128
    scan_part1_kernel<<<16384, 64, 0, stream>>>(ws + DT_S, ws + E0, ws + D0, ws + P_MAL,
                                                ws + P_S, ws + H_S, 2048, 16, 128);
    scan_combine_kernel<<<1024, 128, 0, stream>>>(ws + P_S, ws + H_S, nullptr, 16);
    scan_emit_kernel<<<16384, 64, 0, stream>>>(ws + DT_S, ws + E0, ws + D0, ws + C0,
                                               ws + P_MAL, ws + P_S, ws + P_MD,
                                               ws + F0, 2048, 16, 128);
    // 7) yo = y @ m_out_w                     F -> A (yo; overwrites dead dt_s)
    gemm_kernel<<<dim3(32, 8, 2), 256, 0, stream>>>(ws + F0, 512, 2048LL * 512, ws + P_MOW, 512,
                                                    nullptr, ws + A0, 512, 2048LL * 512,
                                                    2048, 512, 0);
    // 8) cls-token rows into SEQ              P -> G (P_s/H_s dead)
    cls_rows_kernel<<<8, 256, 0, stream>>>(ws + P_CLS1, ws + P_CLS2, ws + G0);
    // 9) softmax + scatter                    A -> G
    softmax_scatter_kernel<<<dim3(2048, 2), 256, 0, stream>>>(ws + A0, ws + G0, 2048);
    // 10) cross in-proj                       G -> C (XZC spans C,D,+head of E)
    gemm_kernel<<<dim3(33, 16, 2), 256, 0, stream>>>(ws + G0, 1024, 2049LL * 1024, ws + P_CINW,
                                                     1024, nullptr, ws + C0, 1024, 2049LL * 1024,
                                                     2049, 1024, 0);
    // 11) cross conv+silu                     C -> A (XSC)
    conv_silu_kernel<<<8196, 256, 0, stream>>>(ws + C0, 1024, 2049LL * 1024, ws + P_CCW,
                                               ws + P_CCB, ws + A0, 2049, 0);
    // 12) cross x_dbl                         A -> B (XDC)
    gemm_kernel<<<dim3(33, 5, 2), 256, 0, stream>>>(ws + A0, 512, 2049LL * 512, ws + P_CXP, 288,
                                                    nullptr, ws + B0, 288, 2049LL * 288,
                                                    2049, 512, 0);
    // 12b) cross dt                           B -> DT_C (after XZC end; no overlap)
    dt_kernel<<<8196, 256, 0, stream>>>(ws + B0, ws + P_CDTW, ws + P_CDTB, ws + DT_C, 2049);
    // 13) cross chunked scan: T=2049, 17 chunks x 128 (last chunk 1 step)
    scan_part1_kernel<<<17408, 64, 0, stream>>>(ws + DT_C, ws + B0, ws + A0, ws + P_CAL,
                                                ws + P_C, ws + H_C, 2049, 17, 128);
    scan_combine_kernel<<<1024, 128, 0, stream>>>(ws + P_C, ws + H_C, ws + HFIN, 17);
    cross_readout_kernel<<<1024, 64, 0, stream>>>(ws + HFIN, ws + B0, ws + A0, ws + C0,
                                                  ws + P_CD, ws + YL0, 2049);
    // 14) out-projection of last rows         YL -> OL
    vecmat_kernel<<<dim3(2, 2), 256, 0, stream>>>(ws + YL0, ws + P_COW, ws + OL0);
    // 15) classifier                          OL -> out (f32)
    final_kernel<<<1, 256, 0, stream>>>(ws + OL0, ws + P_CLSW, ws + P_CLSB, out);
}

// Round 7
// 956.768 us; speedup vs baseline: 5.5207x; 1.1699x over previous
//
#include <hip/hip_runtime.h>
#include <hip/hip_bf16.h>

#define TC    2049
#define DI    512
#define NS    128
#define XPN   288   // DT_RANK + 2*N_STATE = 32 + 256

__device__ __forceinline__ float us2f(unsigned short u) {
    union { unsigned int i; float f; } v; v.i = ((unsigned int)u) << 16; return v.f;
}
__device__ __forceinline__ float sigm(float x) { return 1.f / (1.f + __expf(-x)); }

// ---------------- dtype sniffing: bf16 inputs (flag=0) vs f32 inputs (flag=1) -----
__global__ void detect_kernel(const unsigned short* __restrict__ x, int* __restrict__ flag) {
    __shared__ int cnt;
    int tid = threadIdx.x;
    if (tid == 0) cnt = 0;
    __syncthreads();
    unsigned short u = x[tid];
    int e = (u >> 7) & 0xFF;
    int insane = (u != 0 && (e < 97 || e > 157)) ? 1 : 0;
    atomicAdd(&cnt, insane);
    __syncthreads();
    if (tid == 0) *flag = (cnt >= 64) ? 1 : 0;
}

// ---------------- widen all inputs to f32 in workspace ----------------
struct WD { const void* src; float* dst; int n; };
struct WDT { WD e[25]; };
__global__ __launch_bounds__(256) void widen_all_kernel(WDT tab, const int* __restrict__ flag) {
    WD d = tab.e[blockIdx.y];
    const int f = *flag;
    const int stride = gridDim.x * 256;
    int i = blockIdx.x * 256 + threadIdx.x;
    if (f) {
        const float* s = (const float*)d.src;
        for (; i < d.n; i += stride) d.dst[i] = s[i];
    } else {
        const unsigned short* s = (const unsigned short*)d.src;
        for (; i < d.n; i += stride) d.dst[i] = us2f(s[i]);
    }
}

// ---------------- f32 GEMM, optional bias + relu, batched over gridDim.z ----------------
__global__ __launch_bounds__(256) void gemm_kernel(
    const float* __restrict__ A, int lda, long long sA,
    const float* __restrict__ W, int N,
    const float* __restrict__ bias,
    float* __restrict__ C, int ldc, long long sC,
    int M, int K, int act)
{
    A += (size_t)blockIdx.z * sA;
    C += (size_t)blockIdx.z * sC;
    __shared__ float As[16][64];   // As[k][m]
    __shared__ float Bs[16][64];   // Bs[k][n]
    const int tid = threadIdx.x;
    const int bm = blockIdx.x * 64;
    const int bn = blockIdx.y * 64;
    const int tx = tid & 15, ty = tid >> 4;
    const int arow = tid >> 2, ak = (tid & 3) << 2;
    const int bk = tid >> 4, bn0 = (tid & 15) << 2;
    float acc[4][4] = {};
    for (int kt = 0; kt < K; kt += 16) {
        float4 av = make_float4(0.f, 0.f, 0.f, 0.f);
        int grow = bm + arow;
        if (grow < M) av = *(const float4*)(A + (size_t)grow * lda + kt + ak);
        float4 bv;
        int gn = bn + bn0;
        const float* wrow = W + (size_t)(kt + bk) * N;
        if (gn + 3 < N) {
            bv = *(const float4*)(wrow + gn);
        } else {
            bv.x = (gn     < N) ? wrow[gn]     : 0.f;
            bv.y = (gn + 1 < N) ? wrow[gn + 1] : 0.f;
            bv.z = (gn + 2 < N) ? wrow[gn + 2] : 0.f;
            bv.w = (gn + 3 < N) ? wrow[gn + 3] : 0.f;
        }
        __syncthreads();
        As[ak][arow]     = av.x;
        As[ak + 1][arow] = av.y;
        As[ak + 2][arow] = av.z;
        As[ak + 3][arow] = av.w;
        *(float4*)&Bs[bk][bn0] = bv;
        __syncthreads();
#pragma unroll
        for (int k = 0; k < 16; ++k) {
            float4 a = *(const float4*)&As[k][ty << 2];
            float4 b = *(const float4*)&Bs[k][tx << 2];
            acc[0][0] += a.x * b.x; acc[0][1] += a.x * b.y; acc[0][2] += a.x * b.z; acc[0][3] += a.x * b.w;
            acc[1][0] += a.y * b.x; acc[1][1] += a.y * b.y; acc[1][2] += a.y * b.z; acc[1][3] += a.y * b.w;
            acc[2][0] += a.z * b.x; acc[2][1] += a.z * b.y; acc[2][2] += a.z * b.z; acc[2][3] += a.z * b.w;
            acc[3][0] += a.w * b.x; acc[3][1] += a.w * b.y; acc[3][2] += a.w * b.z; acc[3][3] += a.w * b.w;
        }
    }
    int gn = bn + (tx << 2);
    float bvals[4] = {0.f, 0.f, 0.f, 0.f};
    if (bias) {
#pragma unroll
        for (int j = 0; j < 4; ++j) if (gn + j < N) bvals[j] = bias[gn + j];
    }
#pragma unroll
    for (int i = 0; i < 4; ++i) {
        int r = bm + (ty << 2) + i;
        if (r < M) {
            float* crow = C + (size_t)r * ldc;
#pragma unroll
            for (int j = 0; j < 4; ++j) {
                if (gn + j < N) {
                    float v = acc[i][j] + bvals[j];
                    if (act == 1) v = fmaxf(v, 0.f);
                    crow[gn + j] = v;
                }
            }
        }
    }
}

// ---------------- causal depthwise conv (K=4) + silu, batched 2 dirs ----------------
__global__ __launch_bounds__(256) void conv_silu_kernel(
    const float* __restrict__ xzbase, int ld, long long bstride,
    const float* __restrict__ conv_w, const float* __restrict__ conv_b,
    float* __restrict__ xs, int T, int rev_mode)
{
    int idx = blockIdx.x * 256 + threadIdx.x;
    if (idx >= 2 * T * DI) return;
    int half = idx / (T * DI);
    int rem = idx - half * T * DI;
    int t = rem >> 9, d = rem & 511;
    const float* xzp = xzbase + (rev_mode ? 0 : (size_t)half * bstride);
    int rev = rev_mode ? half : 0;
    float acc = conv_b[d];
#pragma unroll
    for (int k = 0; k < 4; ++k) {
        int tt = t - 3 + k;
        if (tt >= 0) {
            int g = rev ? (T - 1 - tt) : tt;
            acc += conv_w[d * 4 + k] * xzp[(size_t)g * ld + d];
        }
    }
    xs[idx] = acc * sigm(acc);
}

// ---------------- dt projection (K=32) + softplus ----------------
__global__ __launch_bounds__(256) void dt_kernel(
    const float* __restrict__ xdbl, const float* __restrict__ dt_w,
    const float* __restrict__ dt_b, float* __restrict__ dtout, int T)
{
    int idx = blockIdx.x * 256 + threadIdx.x;
    if (idx >= 2 * T * DI) return;
    int half = idx / (T * DI);
    int rem = idx - half * T * DI;
    int t = rem >> 9, j = rem & 511;
    const float* a = xdbl + (size_t)half * T * XPN + (size_t)t * XPN;
    float acc = dt_b[j];
#pragma unroll
    for (int k = 0; k < 32; ++k) acc += a[k] * dt_w[k * DI + j];
    dtout[idx] = (acc > 20.f) ? acc : log1pf(__expf(acc));
}

// ---------------- chunked scan pass 1: per-chunk decay product + zero-seeded partial ----
__global__ __launch_bounds__(64) void scan_part1_kernel(
    const float* __restrict__ dt, const float* __restrict__ xdbl,
    const float* __restrict__ xs, const float* __restrict__ A_log,
    float* __restrict__ P, float* __restrict__ H, int T, int NC, int LC)
{
    int b = blockIdx.x;
    int c = b % NC;
    int hd = b / NC;
    int half = hd >> 9, d = hd & 511;
    int lane = threadIdx.x;
    dt   += (size_t)half * T * DI;
    xs   += (size_t)half * T * DI;
    xdbl += (size_t)half * T * XPN;
    const float a0 = -__expf(A_log[d * NS + lane]);
    const float a1 = -__expf(A_log[d * NS + 64 + lane]);
    float P0 = 1.f, P1 = 1.f, h0 = 0.f, h1 = 0.f;
    int t0 = c * LC, t1 = min(T, t0 + LC);
    for (int t = t0; t < t1; ++t) {
        const float* row = xdbl + (size_t)t * XPN;
        float dv = dt[(size_t)t * DI + d];
        float xv = xs[(size_t)t * DI + d];
        float B0 = row[32 + lane], B1 = row[96 + lane];
        float e0 = __expf(dv * a0), e1 = __expf(dv * a1);
        float u = dv * xv;
        h0 = h0 * e0 + u * B0;
        h1 = h1 * e1 + u * B1;
        P0 *= e0; P1 *= e1;
    }
    size_t base = ((size_t)hd * NC + c) * 128;
    P[base + lane] = P0;       P[base + 64 + lane] = P1;
    H[base + lane] = h0;       H[base + 64 + lane] = h1;
}

// ---------------- chunked scan pass 2: serial combine across chunks ----------------
__global__ __launch_bounds__(128) void scan_combine_kernel(
    float* __restrict__ P, const float* __restrict__ H,
    float* __restrict__ Hfinal, int NC)
{
    int hd = blockIdx.x;
    int n = threadIdx.x;
    size_t base = (size_t)hd * NC * 128 + n;
    float h = 0.f;
    for (int c = 0; c < NC; ++c) {
        size_t off = base + (size_t)c * 128;
        float p = P[off];
        float hh = H[off];
        P[off] = h;                // h_start for chunk c (exclusive prefix)
        h = p * h + hh;
    }
    if (Hfinal) Hfinal[(size_t)hd * 128 + n] = h;
}

// ---------------- chunked scan pass 3: replay with seed, emit RAW half-sums ----------
// lanes 0 / 32 write the two 32-lane partial sums; gate_kernel combines + gates.
__global__ __launch_bounds__(64) void scan_emit_kernel(
    const float* __restrict__ dt, const float* __restrict__ xdbl,
    const float* __restrict__ xs, const float* __restrict__ A_log,
    const float* __restrict__ Hstart,
    float* __restrict__ y0, float* __restrict__ y1, int T, int NC, int LC)
{
    int b = blockIdx.x;
    int c = b % NC;
    int hd = b / NC;
    int half = hd >> 9, d = hd & 511;
    int lane = threadIdx.x;
    dt   += (size_t)half * T * DI;
    xs   += (size_t)half * T * DI;
    xdbl += (size_t)half * T * XPN;
    y0   += (size_t)half * T * DI;
    y1   += (size_t)half * T * DI;
    const float a0 = -__expf(A_log[d * NS + lane]);
    const float a1 = -__expf(A_log[d * NS + 64 + lane]);
    size_t base = ((size_t)hd * NC + c) * 128;
    float h0 = Hstart[base + lane];
    float h1 = Hstart[base + 64 + lane];
    float* yout = (lane == 0) ? y0 : y1;   // only lanes 0 / 32 store
    int t0 = c * LC, t1 = min(T, t0 + LC);
    for (int t = t0; t < t1; ++t) {
        const float* row = xdbl + (size_t)t * XPN;
        float dv = dt[(size_t)t * DI + d];
        float xv = xs[(size_t)t * DI + d];
        float B0 = row[32 + lane],  B1 = row[96 + lane];
        float C0 = row[160 + lane], C1 = row[224 + lane];
        float e0 = __expf(dv * a0), e1 = __expf(dv * a1);
        float u = dv * xv;
        h0 = h0 * e0 + u * B0;
        h1 = h1 * e1 + u * B1;
        float p = h0 * C0 + h1 * C1;
        // 5-step xor butterfly: stays within each 32-lane half
        p += __shfl_xor(p, 1, 64);
        p += __shfl_xor(p, 2, 64);
        p += __shfl_xor(p, 4, 64);
        p += __shfl_xor(p, 8, 64);
        p += __shfl_xor(p, 16, 64);
        if ((lane & 31) == 0) yout[(size_t)t * DI + d] = p;
    }
}

// ---------------- gate: y = (y0+y1 + xs*D) * silu(z[flip]) ----------------
__global__ __launch_bounds__(256) void gate_kernel(
    float* __restrict__ y, const float* __restrict__ y1,
    const float* __restrict__ xs, const float* __restrict__ xz,
    const float* __restrict__ Dp, int T)
{
    int idx = blockIdx.x * 256 + threadIdx.x;
    if (idx >= 2 * T * DI) return;
    int half = idx / (T * DI);
    int rem = idx - half * T * DI;
    int t = rem >> 9, d = rem & 511;
    int tg = half ? (T - 1 - t) : t;
    float z = xz[(size_t)tg * 1024 + 512 + d];
    float p = y[idx] + y1[idx] + xs[idx] * Dp[d];
    y[idx] = p * (z * sigm(z));
}

// ---------------- cross: last-step readout from final state + gating ----------------
__global__ __launch_bounds__(64) void cross_readout_kernel(
    const float* __restrict__ Hfinal, const float* __restrict__ xdbl,
    const float* __restrict__ xs, const float* __restrict__ xz,
    const float* __restrict__ Dp, float* __restrict__ ylast, int T)
{
    int hd = blockIdx.x;
    int half = hd >> 9, d = hd & 511;
    int lane = threadIdx.x;
    xdbl += (size_t)half * T * XPN;
    xs   += (size_t)half * T * DI;
    xz   += (size_t)half * T * 1024;
    float h0 = Hfinal[(size_t)hd * 128 + lane];
    float h1 = Hfinal[(size_t)hd * 128 + 64 + lane];
    const float* xl = xdbl + (size_t)(T - 1) * XPN;
    float p = h0 * xl[160 + lane] + h1 * xl[224 + lane];
#pragma unroll
    for (int off = 32; off > 0; off >>= 1) p += __shfl_down(p, off, 64);
    if (lane == 0) {
        float xlast = xs[(size_t)(T - 1) * DI + d];
        float zl = xz[(size_t)(T - 1) * 1024 + 512 + d];
        ylast[half * DI + d] = (p + xlast * Dp[d]) * (zl * sigm(zl));
    }
}

// ---------------- row softmax + scatter into both cross sequences ----------------
__global__ __launch_bounds__(256) void softmax_scatter_kernel(
    const float* __restrict__ yo, float* __restrict__ seq, int T)
{
    __shared__ float sm[4];
    const int t = blockIdx.x, half = blockIdx.y, tid = threadIdx.x;
    const float* row = yo + (size_t)half * T * DI + (size_t)t * DI;
    float v0 = row[tid], v1 = row[tid + 256];
    float m = fmaxf(v0, v1);
#pragma unroll
    for (int o = 32; o > 0; o >>= 1) m = fmaxf(m, __shfl_xor(m, o, 64));
    if ((tid & 63) == 0) sm[tid >> 6] = m;
    __syncthreads();
    m = fmaxf(fmaxf(sm[0], sm[1]), fmaxf(sm[2], sm[3]));
    __syncthreads();
    float e0 = __expf(v0 - m), e1 = __expf(v1 - m);
    float s = e0 + e1;
#pragma unroll
    for (int o = 32; o > 0; o >>= 1) s += __shfl_xor(s, o, 64);
    if ((tid & 63) == 0) sm[tid >> 6] = s;
    __syncthreads();
    s = sm[0] + sm[1] + sm[2] + sm[3];
    float inv = 1.f / s;
    e0 *= inv; e1 *= inv;
    float* seq_fi = seq;
    float* seq_if = seq + (size_t)TC * 1024;
    if (half == 0) {
        float* d1 = seq_fi + (size_t)t * 1024;
        float* d2 = seq_if + (size_t)t * 1024 + 512;
        d1[tid] = e0; d1[tid + 256] = e1;
        d2[tid] = e0; d2[tid + 256] = e1;
    } else {
        int tg = T - 1 - t;
        float* d1 = seq_fi + (size_t)tg * 1024 + 512;
        float* d2 = seq_if + (size_t)tg * 1024;
        d1[tid] = e0; d1[tid + 256] = e1;
        d2[tid] = e0; d2[tid + 256] = e1;
    }
}

// ---------------- cls-token rows of the two sequences ----------------
__global__ __launch_bounds__(256) void cls_rows_kernel(
    const float* __restrict__ cls1, const float* __restrict__ cls2,
    float* __restrict__ seq)
{
    int i = blockIdx.x * 256 + threadIdx.x;   // 0..2047
    if (i < 1024)
        seq[(size_t)(TC - 1) * 1024 + i] = cls1[i];
    else
        seq[(size_t)TC * 1024 + (size_t)(TC - 1) * 1024 + (i - 1024)] = cls2[i - 1024];
}

// ---------------- vec [512] @ out_w [512,512] -> [512] ----------------
__global__ __launch_bounds__(256) void vecmat_kernel(
    const float* __restrict__ ylast, const float* __restrict__ Wout,
    float* __restrict__ olast)
{
    int half = blockIdx.y;
    int j = blockIdx.x * 256 + threadIdx.x;
    const float* v = ylast + half * DI;
    float acc = 0.f;
    for (int k = 0; k < DI; ++k) acc += v[k] * Wout[k * DI + j];
    olast[half * DI + j] = acc;
}

// ---------------- final classifier -> f32 [2] ----------------
__global__ __launch_bounds__(256) void final_kernel(
    const float* __restrict__ ol, const float* __restrict__ cw,
    const float* __restrict__ cb, float* __restrict__ out)
{
    __shared__ float s0[4], s1[4];
    int tid = threadIdx.x;
    float a0 = 0.f, a1 = 0.f;
    for (int j = tid; j < 1024; j += 256) {
        float v = ol[j];
        a0 += v * cw[2 * j];
        a1 += v * cw[2 * j + 1];
    }
#pragma unroll
    for (int o = 32; o > 0; o >>= 1) { a0 += __shfl_xor(a0, o, 64); a1 += __shfl_xor(a1, o, 64); }
    if ((tid & 63) == 0) { s0[tid >> 6] = a0; s1[tid >> 6] = a1; }
    __syncthreads();
    if (tid == 0) {
        out[0] = s0[0] + s0[1] + s0[2] + s0[3] + cb[0];
        out[1] = s1[0] + s1[1] + s1[2] + s1[3] + cb[1];
    }
}

extern "C" void kernel_launch(void* const* d_in, const int* in_sizes, int n_in,
                              void* d_out, int out_size, void* d_ws, size_t ws_size,
                              hipStream_t stream)
{
    float* out = (float*)d_out;
    float* ws = (float*)d_ws;

    // ---- input-order resolution via in_sizes (dict vs signature order) ----
    static const int sig_map[25] = {0,1,2,3,4,23,24,5,6,7,8,9,10,11,12,13,
                                    14,15,16,17,18,19,20,21,22};
    int idx[25];
    bool dict_order = (n_in >= 7 && in_sizes[6] == 2);
    for (int i = 0; i < 25; ++i) idx[i] = dict_order ? i : sig_map[i];

    // ---- aliased workspace layout (f32 elements) ----
    const size_t A0 = 0;         // x(f32) -> dt_simple -> yo -> XSC          (2,098,176)
    const size_t B0 = 2098176;   // f -> XDC                                  (1,180,224)
    const size_t C0 = 3278400;   // XZS / XZC (XZC spans ..7,474,752)         (2,097,152)
    const size_t D0 = 5375552;   // XS                                        (2,097,152)
    const size_t E0 = 7472704;   // XDBL                                      (1,179,648)
    const size_t F0 = 8652352;   // y0 / YS                                   (2,097,152)
    const size_t G0 = 10749504;  // P_S | H_S(y1)  -> SEQ                     (4,196,352)
    const size_t YL0 = 14945856; // 1024
    const size_t OL0 = 14946880; // 1024
    // simple-scan scratch:
    const size_t DT_S = A0;                  // x dead after step 2
    const size_t P_S  = G0;                  // 2,097,152 (SEQ not yet live)
    const size_t H_S  = G0 + 2097152;        // 2,097,152 ; reused as y1 after combine
    // cross-scan scratch (after live XZC end = 7,474,752):
    const size_t DT_C = 7474752;             // -> ends  9,572,928
    const size_t P_C  = 9572928;             // -> ends 11,801,152
    const size_t H_C  = 11801152;            // -> ends 14,029,376
    const size_t HFIN = 14029376;            // -> ends 14,160,448 < YL0
    size_t o = 14947904;
    const size_t P_FEATW = o; o += 524288;
    const size_t P_FEATB = o; o += 512;
    const size_t P_CLS1  = o; o += 1024;
    const size_t P_CLS2  = o; o += 1024;
    const size_t P_CLSW  = o; o += 2048;
    const size_t P_CLSB  = o; o += 4;
    const size_t P_MINW  = o; o += 524288;
    const size_t P_MCW   = o; o += 2048;
    const size_t P_MCB   = o; o += 512;
    const size_t P_MXP   = o; o += 147456;
    const size_t P_MDTW  = o; o += 16384;
    const size_t P_MDTB  = o; o += 512;
    const size_t P_MAL   = o; o += 65536;
    const size_t P_MD    = o; o += 512;
    const size_t P_MOW   = o; o += 262144;
    const size_t P_CINW  = o; o += 1048576;
    const size_t P_CCW   = o; o += 2048;
    const size_t P_CCB   = o; o += 512;
    const size_t P_CXP   = o; o += 147456;
    const size_t P_CDTW  = o; o += 16384;
    const size_t P_CDTB  = o; o += 512;
    const size_t P_CAL   = o; o += 65536;
    const size_t P_CD    = o; o += 512;
    const size_t P_COW   = o; o += 262144;
    const size_t OFF_FLAG = o;               // 1 int

    int* flagp = (int*)(ws + OFF_FLAG);

    // 0) detect input dtype
    detect_kernel<<<1, 256, 0, stream>>>((const unsigned short*)d_in[idx[0]], flagp);

    // 1) widen all 25 inputs to f32
    WDT tab;
    const int ns[25] = {2097152, 524288, 512, 1024, 1024, 2048, 2,
                        524288, 2048, 512, 147456, 16384, 512, 65536, 512, 262144,
                        1048576, 2048, 512, 147456, 16384, 512, 65536, 512, 262144};
    float* dsts[25] = {
        ws + A0, ws + P_FEATW, ws + P_FEATB, ws + P_CLS1, ws + P_CLS2,
        ws + P_CLSW, ws + P_CLSB,
        ws + P_MINW, ws + P_MCW, ws + P_MCB, ws + P_MXP, ws + P_MDTW, ws + P_MDTB,
        ws + P_MAL, ws + P_MD, ws + P_MOW,
        ws + P_CINW, ws + P_CCW, ws + P_CCB, ws + P_CXP, ws + P_CDTW, ws + P_CDTB,
        ws + P_CAL, ws + P_CD, ws + P_COW};
    for (int i = 0; i < 25; ++i) {
        tab.e[i].src = d_in[idx[i]];
        tab.e[i].dst = dsts[i];
        tab.e[i].n = ns[i];
    }
    widen_all_kernel<<<dim3(128, 25), 256, 0, stream>>>(tab, flagp);

    // 2) f = relu(x @ feat_w + feat_b)        A -> B
    gemm_kernel<<<dim3(32, 8, 1), 256, 0, stream>>>(ws + A0, 1024, 0, ws + P_FEATW, 512,
                                                    ws + P_FEATB, ws + B0, 512, 0, 2048, 1024, 1);
    // 3) xz = f @ m_in_w                      B -> C
    gemm_kernel<<<dim3(32, 16, 1), 256, 0, stream>>>(ws + B0, 512, 0, ws + P_MINW, 1024, nullptr,
                                                     ws + C0, 1024, 0, 2048, 512, 0);
    // 4) conv+silu, both directions           C -> D
    conv_silu_kernel<<<8192, 256, 0, stream>>>(ws + C0, 1024, 0, ws + P_MCW, ws + P_MCB,
                                               ws + D0, 2048, 1);
    // 5) x_dbl = xs @ m_xproj_w               D -> E
    gemm_kernel<<<dim3(32, 5, 2), 256, 0, stream>>>(ws + D0, 512, 2048LL * 512, ws + P_MXP, 288,
                                                    nullptr, ws + E0, 288, 2048LL * 288,
                                                    2048, 512, 0);
    // 5b) dt = softplus(x_dbl[:, :32] @ dt_w + dt_b)   E -> DT_S (A)
    dt_kernel<<<8192, 256, 0, stream>>>(ws + E0, ws + P_MDTW, ws + P_MDTB, ws + DT_S, 2048);
    // 6) chunked scan: T=2048, 16 chunks x 128
    scan_part1_kernel<<<16384, 64, 0, stream>>>(ws + DT_S, ws + E0, ws + D0, ws + P_MAL,
                                                ws + P_S, ws + H_S, 2048, 16, 128);
    scan_combine_kernel<<<1024, 128, 0, stream>>>(ws + P_S, ws + H_S, nullptr, 16);
    scan_emit_kernel<<<16384, 64, 0, stream>>>(ws + DT_S, ws + E0, ws + D0, ws + P_MAL,
                                               ws + P_S, ws + F0, ws + H_S, 2048, 16, 128);
    // 6b) gate: y = (y0+y1 + xs*D)*silu(z)    F,H_S,D,C -> F
    gate_kernel<<<8192, 256, 0, stream>>>(ws + F0, ws + H_S, ws + D0, ws + C0, ws + P_MD, 2048);
    // 7) yo = y @ m_out_w                     F -> A (yo; overwrites dead dt_s)
    gemm_kernel<<<dim3(32, 8, 2), 256, 0, stream>>>(ws + F0, 512, 2048LL * 512, ws + P_MOW, 512,
                                                    nullptr, ws + A0, 512, 2048LL * 512,
                                                    2048, 512, 0);
    // 8) cls-token rows into SEQ              P -> G (scan scratch dead)
    cls_rows_kernel<<<8, 256, 0, stream>>>(ws + P_CLS1, ws + P_CLS2, ws + G0);
    // 9) softmax + scatter                    A -> G
    softmax_scatter_kernel<<<dim3(2048, 2), 256, 0, stream>>>(ws + A0, ws + G0, 2048);
    // 10) cross in-proj                       G -> C (XZC spans C,D,+head of E)
    gemm_kernel<<<dim3(33, 16, 2), 256, 0, stream>>>(ws + G0, 1024, 2049LL * 1024, ws + P_CINW,
                                                     1024, nullptr, ws + C0, 1024, 2049LL * 1024,
                                                     2049, 1024, 0);
    // 11) cross conv+silu                     C -> A (XSC)
    conv_silu_kernel<<<8196, 256, 0, stream>>>(ws + C0, 1024, 2049LL * 1024, ws + P_CCW,
                                               ws + P_CCB, ws + A0, 2049, 0);
    // 12) cross x_dbl                         A -> B (XDC)
    gemm_kernel<<<dim3(33, 5, 2), 256, 0, stream>>>(ws + A0, 512, 2049LL * 512, ws + P_CXP, 288,
                                                    nullptr, ws + B0, 288, 2049LL * 288,
                                                    2049, 512, 0);
    // 12b) cross dt                           B -> DT_C
    dt_kernel<<<8196, 256, 0, stream>>>(ws + B0, ws + P_CDTW, ws + P_CDTB, ws + DT_C, 2049);
    // 13) cross chunked scan: T=2049, 17 chunks x 128
    scan_part1_kernel<<<17408, 64, 0, stream>>>(ws + DT_C, ws + B0, ws + A0, ws + P_CAL,
                                                ws + P_C, ws + H_C, 2049, 17, 128);
    scan_combine_kernel<<<1024, 128, 0, stream>>>(ws + P_C, ws + H_C, ws + HFIN, 17);
    cross_readout_kernel<<<1024, 64, 0, stream>>>(ws + HFIN, ws + B0, ws + A0, ws + C0,
                                                  ws + P_CD, ws + YL0, 2049);
    // 14) out-projection of last rows         YL -> OL
    vecmat_kernel<<<dim3(2, 2), 256, 0, stream>>>(ws + YL0, ws + P_COW, ws + OL0);
    // 15) classifier                          OL -> out (f32)
    final_kernel<<<1, 256, 0, stream>>>(ws + OL0, ws + P_CLSW, ws + P_CLSB, out);
}

// Round 8
// 794.116 us; speedup vs baseline: 6.6514x; 1.2048x over previous
//
#include <hip/hip_runtime.h>
#include <hip/hip_bf16.h>

#define TC    2049
#define DI    512
#define NS    128
#define XPN   288   // DT_RANK + 2*N_STATE = 32 + 256

typedef short bfx8 __attribute__((ext_vector_type(8)));
typedef float f32x4 __attribute__((ext_vector_type(4)));

__device__ __forceinline__ float us2f(unsigned short u) {
    union { unsigned int i; float f; } v; v.i = ((unsigned int)u) << 16; return v.f;
}
__device__ __forceinline__ unsigned short f2bf(float f) {
    unsigned int u = __float_as_uint(f);
    u = (u + 0x7FFF + ((u >> 16) & 1)) >> 16;   // round-to-nearest-even
    return (unsigned short)u;
}
__device__ __forceinline__ float sigm(float x) { return 1.f / (1.f + __expf(-x)); }

// ---------------- dtype sniffing: bf16 inputs (flag=0) vs f32 inputs (flag=1) -----
__global__ void detect_kernel(const unsigned short* __restrict__ x, int* __restrict__ flag) {
    __shared__ int cnt;
    int tid = threadIdx.x;
    if (tid == 0) cnt = 0;
    __syncthreads();
    unsigned short u = x[tid];
    int e = (u >> 7) & 0xFF;
    int insane = (u != 0 && (e < 97 || e > 157)) ? 1 : 0;
    atomicAdd(&cnt, insane);
    __syncthreads();
    if (tid == 0) *flag = (cnt >= 64) ? 1 : 0;
}

// ---------------- widen all inputs to f32 in workspace ----------------
struct WD { const void* src; float* dst; int n; };
struct WDT { WD e[25]; };
__global__ __launch_bounds__(256) void widen_all_kernel(WDT tab, const int* __restrict__ flag) {
    WD d = tab.e[blockIdx.y];
    const int f = *flag;
    const int stride = gridDim.x * 256;
    int i = blockIdx.x * 256 + threadIdx.x;
    if (f) {
        const float* s = (const float*)d.src;
        for (; i < d.n; i += stride) d.dst[i] = s[i];
    } else {
        const unsigned short* s = (const unsigned short*)d.src;
        for (; i < d.n; i += stride) d.dst[i] = us2f(s[i]);
    }
}

// ---------------- bf16-MFMA GEMM (f32 in/out, bf16 matrix cores) ------------------
// C[m,n] = act( sum_k A[m,k]*W[k,n] + bias[n] ), batched over gridDim.z.
// 64x64 tile, 4 waves, K-panel 32. LDS rows padded to 40 bf16 (anti-conflict).
__global__ __launch_bounds__(256) void gemm_mfma_kernel(
    const float* __restrict__ A, int lda, long long sA,
    const float* __restrict__ W, int N,
    const float* __restrict__ bias,
    float* __restrict__ C, int ldc, long long sC,
    int M, int K, int act)
{
    A += (size_t)blockIdx.z * sA;
    C += (size_t)blockIdx.z * sC;
    __shared__ __align__(16) unsigned short As[64][40];   // [m][k] bf16
    __shared__ __align__(16) unsigned short Bs[64][40];   // [n][k] bf16 (transposed)
    const int tid = threadIdx.x;
    const int wave = tid >> 6, lane = tid & 63;
    const int bm = blockIdx.x * 64, bn = blockIdx.y * 64;
    const int col = lane & 15, quad = lane >> 4;

    f32x4 acc[4] = {{0.f,0.f,0.f,0.f},{0.f,0.f,0.f,0.f},{0.f,0.f,0.f,0.f},{0.f,0.f,0.f,0.f}};

    const int ar = tid >> 2, ak = (tid & 3) << 3;        // A: row 0..63, k-chunk of 8
    const int kr = tid >> 3, nb = (tid & 7) << 3;        // W: k-row 0..31, n-chunk of 8

    for (int kt = 0; kt < K; kt += 32) {
        // ---- load globals (f32) ----
        float va[8];
        int gm = bm + ar;
        if (gm < M) {
            const float* ap = A + (size_t)gm * lda + kt + ak;
            float4 v0 = *(const float4*)ap;
            float4 v1 = *(const float4*)(ap + 4);
            va[0]=v0.x; va[1]=v0.y; va[2]=v0.z; va[3]=v0.w;
            va[4]=v1.x; va[5]=v1.y; va[6]=v1.z; va[7]=v1.w;
        } else {
#pragma unroll
            for (int j = 0; j < 8; ++j) va[j] = 0.f;
        }
        float vb[8];
        int gn0 = bn + nb;
        const float* wp = W + (size_t)(kt + kr) * N + gn0;
        if (gn0 + 7 < N) {
            float4 w0 = *(const float4*)wp;
            float4 w1 = *(const float4*)(wp + 4);
            vb[0]=w0.x; vb[1]=w0.y; vb[2]=w0.z; vb[3]=w0.w;
            vb[4]=w1.x; vb[5]=w1.y; vb[6]=w1.z; vb[7]=w1.w;
        } else {
#pragma unroll
            for (int j = 0; j < 8; ++j) vb[j] = (gn0 + j < N) ? wp[j] : 0.f;
        }
        __syncthreads();   // protect previous iteration's LDS reads
        // ---- stage to LDS as bf16 ----
        bfx8 apk;
#pragma unroll
        for (int j = 0; j < 8; ++j) apk[j] = (short)f2bf(va[j]);
        *(bfx8*)&As[ar][ak] = apk;
#pragma unroll
        for (int j = 0; j < 8; ++j) Bs[nb + j][kr] = f2bf(vb[j]);
        __syncthreads();
        // ---- MFMA: wave handles rows [wave*16, wave*16+16) x 64 cols ----
        bfx8 af = *(const bfx8*)&As[wave * 16 + col][quad << 3];
#pragma unroll
        for (int ct = 0; ct < 4; ++ct) {
            bfx8 bf = *(const bfx8*)&Bs[ct * 16 + col][quad << 3];
            acc[ct] = __builtin_amdgcn_mfma_f32_16x16x32_bf16(af, bf, acc[ct], 0, 0, 0);
        }
    }
    // ---- epilogue: C/D layout col=lane&15, row=quad*4+reg ----
#pragma unroll
    for (int ct = 0; ct < 4; ++ct) {
        int gn = bn + ct * 16 + col;
        if (gn >= N) continue;
        float bv = bias ? bias[gn] : 0.f;
#pragma unroll
        for (int r = 0; r < 4; ++r) {
            int gm = bm + wave * 16 + quad * 4 + r;
            if (gm < M) {
                float v = acc[ct][r] + bv;
                if (act == 1) v = fmaxf(v, 0.f);
                C[(size_t)gm * ldc + gn] = v;
            }
        }
    }
}

// ---------------- causal depthwise conv (K=4) + silu, batched 2 dirs ----------------
__global__ __launch_bounds__(256) void conv_silu_kernel(
    const float* __restrict__ xzbase, int ld, long long bstride,
    const float* __restrict__ conv_w, const float* __restrict__ conv_b,
    float* __restrict__ xs, int T, int rev_mode)
{
    int idx = blockIdx.x * 256 + threadIdx.x;
    if (idx >= 2 * T * DI) return;
    int half = idx / (T * DI);
    int rem = idx - half * T * DI;
    int t = rem >> 9, d = rem & 511;
    const float* xzp = xzbase + (rev_mode ? 0 : (size_t)half * bstride);
    int rev = rev_mode ? half : 0;
    float acc = conv_b[d];
#pragma unroll
    for (int k = 0; k < 4; ++k) {
        int tt = t - 3 + k;
        if (tt >= 0) {
            int g = rev ? (T - 1 - tt) : tt;
            acc += conv_w[d * 4 + k] * xzp[(size_t)g * ld + d];
        }
    }
    xs[idx] = acc * sigm(acc);
}

// ---------------- dt projection (K=32) + softplus ----------------
__global__ __launch_bounds__(256) void dt_kernel(
    const float* __restrict__ xdbl, const float* __restrict__ dt_w,
    const float* __restrict__ dt_b, float* __restrict__ dtout, int T)
{
    int idx = blockIdx.x * 256 + threadIdx.x;
    if (idx >= 2 * T * DI) return;
    int half = idx / (T * DI);
    int rem = idx - half * T * DI;
    int t = rem >> 9, j = rem & 511;
    const float* a = xdbl + (size_t)half * T * XPN + (size_t)t * XPN;
    float acc = dt_b[j];
#pragma unroll
    for (int k = 0; k < 32; ++k) acc += a[k] * dt_w[k * DI + j];
    dtout[idx] = (acc > 20.f) ? acc : log1pf(__expf(acc));
}

// ---------------- chunked scan pass 1: per-chunk decay product + zero-seeded partial ----
__global__ __launch_bounds__(64) void scan_part1_kernel(
    const float* __restrict__ dt, const float* __restrict__ xdbl,
    const float* __restrict__ xs, const float* __restrict__ A_log,
    float* __restrict__ P, float* __restrict__ H, int T, int NC, int LC)
{
    int b = blockIdx.x;
    int c = b % NC;
    int hd = b / NC;
    int half = hd >> 9, d = hd & 511;
    int lane = threadIdx.x;
    dt   += (size_t)half * T * DI;
    xs   += (size_t)half * T * DI;
    xdbl += (size_t)half * T * XPN;
    const float a0 = -__expf(A_log[d * NS + lane]);
    const float a1 = -__expf(A_log[d * NS + 64 + lane]);
    float P0 = 1.f, P1 = 1.f, h0 = 0.f, h1 = 0.f;
    int t0 = c * LC, t1 = min(T, t0 + LC);
    for (int t = t0; t < t1; ++t) {
        const float* row = xdbl + (size_t)t * XPN;
        float dv = dt[(size_t)t * DI + d];
        float xv = xs[(size_t)t * DI + d];
        float B0 = row[32 + lane], B1 = row[96 + lane];
        float e0 = __expf(dv * a0), e1 = __expf(dv * a1);
        float u = dv * xv;
        h0 = h0 * e0 + u * B0;
        h1 = h1 * e1 + u * B1;
        P0 *= e0; P1 *= e1;
    }
    size_t base = ((size_t)hd * NC + c) * 128;
    P[base + lane] = P0;       P[base + 64 + lane] = P1;
    H[base + lane] = h0;       H[base + 64 + lane] = h1;
}

// ---------------- chunked scan pass 2: serial combine across chunks ----------------
__global__ __launch_bounds__(128) void scan_combine_kernel(
    float* __restrict__ P, const float* __restrict__ H,
    float* __restrict__ Hfinal, int NC)
{
    int hd = blockIdx.x;
    int n = threadIdx.x;
    size_t base = (size_t)hd * NC * 128 + n;
    float h = 0.f;
    for (int c = 0; c < NC; ++c) {
        size_t off = base + (size_t)c * 128;
        float p = P[off];
        float hh = H[off];
        P[off] = h;                // h_start for chunk c (exclusive prefix)
        h = p * h + hh;
    }
    if (Hfinal) Hfinal[(size_t)hd * 128 + n] = h;
}

// ---------------- chunked scan pass 3: replay with seed, emit RAW half-sums ----------
__global__ __launch_bounds__(64) void scan_emit_kernel(
    const float* __restrict__ dt, const float* __restrict__ xdbl,
    const float* __restrict__ xs, const float* __restrict__ A_log,
    const float* __restrict__ Hstart,
    float* __restrict__ y0, float* __restrict__ y1, int T, int NC, int LC)
{
    int b = blockIdx.x;
    int c = b % NC;
    int hd = b / NC;
    int half = hd >> 9, d = hd & 511;
    int lane = threadIdx.x;
    dt   += (size_t)half * T * DI;
    xs   += (size_t)half * T * DI;
    xdbl += (size_t)half * T * XPN;
    y0   += (size_t)half * T * DI;
    y1   += (size_t)half * T * DI;
    const float a0 = -__expf(A_log[d * NS + lane]);
    const float a1 = -__expf(A_log[d * NS + 64 + lane]);
    size_t base = ((size_t)hd * NC + c) * 128;
    float h0 = Hstart[base + lane];
    float h1 = Hstart[base + 64 + lane];
    float* yout = (lane == 0) ? y0 : y1;   // only lanes 0 / 32 store
    int t0 = c * LC, t1 = min(T, t0 + LC);
    for (int t = t0; t < t1; ++t) {
        const float* row = xdbl + (size_t)t * XPN;
        float dv = dt[(size_t)t * DI + d];
        float xv = xs[(size_t)t * DI + d];
        float B0 = row[32 + lane],  B1 = row[96 + lane];
        float C0 = row[160 + lane], C1 = row[224 + lane];
        float e0 = __expf(dv * a0), e1 = __expf(dv * a1);
        float u = dv * xv;
        h0 = h0 * e0 + u * B0;
        h1 = h1 * e1 + u * B1;
        float p = h0 * C0 + h1 * C1;
        p += __shfl_xor(p, 1, 64);
        p += __shfl_xor(p, 2, 64);
        p += __shfl_xor(p, 4, 64);
        p += __shfl_xor(p, 8, 64);
        p += __shfl_xor(p, 16, 64);
        if ((lane & 31) == 0) yout[(size_t)t * DI + d] = p;
    }
}

// ---------------- gate: y = (y0+y1 + xs*D) * silu(z[flip]) ----------------
__global__ __launch_bounds__(256) void gate_kernel(
    float* __restrict__ y, const float* __restrict__ y1,
    const float* __restrict__ xs, const float* __restrict__ xz,
    const float* __restrict__ Dp, int T)
{
    int idx = blockIdx.x * 256 + threadIdx.x;
    if (idx >= 2 * T * DI) return;
    int half = idx / (T * DI);
    int rem = idx - half * T * DI;
    int t = rem >> 9, d = rem & 511;
    int tg = half ? (T - 1 - t) : t;
    float z = xz[(size_t)tg * 1024 + 512 + d];
    float p = y[idx] + y1[idx] + xs[idx] * Dp[d];
    y[idx] = p * (z * sigm(z));
}

// ---------------- cross: last-step readout from final state + gating ----------------
__global__ __launch_bounds__(64) void cross_readout_kernel(
    const float* __restrict__ Hfinal, const float* __restrict__ xdbl,
    const float* __restrict__ xs, const float* __restrict__ xz,
    const float* __restrict__ Dp, float* __restrict__ ylast, int T)
{
    int hd = blockIdx.x;
    int half = hd >> 9, d = hd & 511;
    int lane = threadIdx.x;
    xdbl += (size_t)half * T * XPN;
    xs   += (size_t)half * T * DI;
    xz   += (size_t)half * T * 1024;
    float h0 = Hfinal[(size_t)hd * 128 + lane];
    float h1 = Hfinal[(size_t)hd * 128 + 64 + lane];
    const float* xl = xdbl + (size_t)(T - 1) * XPN;
    float p = h0 * xl[160 + lane] + h1 * xl[224 + lane];
#pragma unroll
    for (int off = 32; off > 0; off >>= 1) p += __shfl_down(p, off, 64);
    if (lane == 0) {
        float xlast = xs[(size_t)(T - 1) * DI + d];
        float zl = xz[(size_t)(T - 1) * 1024 + 512 + d];
        ylast[half * DI + d] = (p + xlast * Dp[d]) * (zl * sigm(zl));
    }
}

// ---------------- row softmax + scatter into both cross sequences ----------------
__global__ __launch_bounds__(256) void softmax_scatter_kernel(
    const float* __restrict__ yo, float* __restrict__ seq, int T)
{
    __shared__ float sm[4];
    const int t = blockIdx.x, half = blockIdx.y, tid = threadIdx.x;
    const float* row = yo + (size_t)half * T * DI + (size_t)t * DI;
    float v0 = row[tid], v1 = row[tid + 256];
    float m = fmaxf(v0, v1);
#pragma unroll
    for (int o = 32; o > 0; o >>= 1) m = fmaxf(m, __shfl_xor(m, o, 64));
    if ((tid & 63) == 0) sm[tid >> 6] = m;
    __syncthreads();
    m = fmaxf(fmaxf(sm[0], sm[1]), fmaxf(sm[2], sm[3]));
    __syncthreads();
    float e0 = __expf(v0 - m), e1 = __expf(v1 - m);
    float s = e0 + e1;
#pragma unroll
    for (int o = 32; o > 0; o >>= 1) s += __shfl_xor(s, o, 64);
    if ((tid & 63) == 0) sm[tid >> 6] = s;
    __syncthreads();
    s = sm[0] + sm[1] + sm[2] + sm[3];
    float inv = 1.f / s;
    e0 *= inv; e1 *= inv;
    float* seq_fi = seq;
    float* seq_if = seq + (size_t)TC * 1024;
    if (half == 0) {
        float* d1 = seq_fi + (size_t)t * 1024;
        float* d2 = seq_if + (size_t)t * 1024 + 512;
        d1[tid] = e0; d1[tid + 256] = e1;
        d2[tid] = e0; d2[tid + 256] = e1;
    } else {
        int tg = T - 1 - t;
        float* d1 = seq_fi + (size_t)tg * 1024 + 512;
        float* d2 = seq_if + (size_t)tg * 1024;
        d1[tid] = e0; d1[tid + 256] = e1;
        d2[tid] = e0; d2[tid + 256] = e1;
    }
}

// ---------------- cls-token rows of the two sequences ----------------
__global__ __launch_bounds__(256) void cls_rows_kernel(
    const float* __restrict__ cls1, const float* __restrict__ cls2,
    float* __restrict__ seq)
{
    int i = blockIdx.x * 256 + threadIdx.x;   // 0..2047
    if (i < 1024)
        seq[(size_t)(TC - 1) * 1024 + i] = cls1[i];
    else
        seq[(size_t)TC * 1024 + (size_t)(TC - 1) * 1024 + (i - 1024)] = cls2[i - 1024];
}

// ---------------- vec [512] @ out_w [512,512] -> [512] ----------------
__global__ __launch_bounds__(256) void vecmat_kernel(
    const float* __restrict__ ylast, const float* __restrict__ Wout,
    float* __restrict__ olast)
{
    int half = blockIdx.y;
    int j = blockIdx.x * 256 + threadIdx.x;
    const float* v = ylast + half * DI;
    float acc = 0.f;
    for (int k = 0; k < DI; ++k) acc += v[k] * Wout[k * DI + j];
    olast[half * DI + j] = acc;
}

// ---------------- final classifier -> f32 [2] ----------------
__global__ __launch_bounds__(256) void final_kernel(
    const float* __restrict__ ol, const float* __restrict__ cw,
    const float* __restrict__ cb, float* __restrict__ out)
{
    __shared__ float s0[4], s1[4];
    int tid = threadIdx.x;
    float a0 = 0.f, a1 = 0.f;
    for (int j = tid; j < 1024; j += 256) {
        float v = ol[j];
        a0 += v * cw[2 * j];
        a1 += v * cw[2 * j + 1];
    }
#pragma unroll
    for (int o = 32; o > 0; o >>= 1) { a0 += __shfl_xor(a0, o, 64); a1 += __shfl_xor(a1, o, 64); }
    if ((tid & 63) == 0) { s0[tid >> 6] = a0; s1[tid >> 6] = a1; }
    __syncthreads();
    if (tid == 0) {
        out[0] = s0[0] + s0[1] + s0[2] + s0[3] + cb[0];
        out[1] = s1[0] + s1[1] + s1[2] + s1[3] + cb[1];
    }
}

extern "C" void kernel_launch(void* const* d_in, const int* in_sizes, int n_in,
                              void* d_out, int out_size, void* d_ws, size_t ws_size,
                              hipStream_t stream)
{
    float* out = (float*)d_out;
    float* ws = (float*)d_ws;

    // ---- input-order resolution via in_sizes (dict vs signature order) ----
    static const int sig_map[25] = {0,1,2,3,4,23,24,5,6,7,8,9,10,11,12,13,
                                    14,15,16,17,18,19,20,21,22};
    int idx[25];
    bool dict_order = (n_in >= 7 && in_sizes[6] == 2);
    for (int i = 0; i < 25; ++i) idx[i] = dict_order ? i : sig_map[i];

    // ---- aliased workspace layout (f32 elements) ----
    const size_t A0 = 0;         // x(f32) -> dt_simple -> yo -> XSC          (2,098,176)
    const size_t B0 = 2098176;   // f -> XDC                                  (1,180,224)
    const size_t C0 = 3278400;   // XZS / XZC (XZC spans ..7,474,752)         (2,097,152)
    const size_t D0 = 5375552;   // XS                                        (2,097,152)
    const size_t E0 = 7472704;   // XDBL                                      (1,179,648)
    const size_t F0 = 8652352;   // y0 / YS                                   (2,097,152)
    const size_t G0 = 10749504;  // P_S | H_S(y1)  -> SEQ                     (4,196,352)
    const size_t YL0 = 14945856; // 1024
    const size_t OL0 = 14946880; // 1024
    const size_t DT_S = A0;
    const size_t P_S  = G0;
    const size_t H_S  = G0 + 2097152;
    const size_t DT_C = 7474752;
    const size_t P_C  = 9572928;
    const size_t H_C  = 11801152;
    const size_t HFIN = 14029376;
    size_t o = 14947904;
    const size_t P_FEATW = o; o += 524288;
    const size_t P_FEATB = o; o += 512;
    const size_t P_CLS1  = o; o += 1024;
    const size_t P_CLS2  = o; o += 1024;
    const size_t P_CLSW  = o; o += 2048;
    const size_t P_CLSB  = o; o += 4;
    const size_t P_MINW  = o; o += 524288;
    const size_t P_MCW   = o; o += 2048;
    const size_t P_MCB   = o; o += 512;
    const size_t P_MXP   = o; o += 147456;
    const size_t P_MDTW  = o; o += 16384;
    const size_t P_MDTB  = o; o += 512;
    const size_t P_MAL   = o; o += 65536;
    const size_t P_MD    = o; o += 512;
    const size_t P_MOW   = o; o += 262144;
    const size_t P_CINW  = o; o += 1048576;
    const size_t P_CCW   = o; o += 2048;
    const size_t P_CCB   = o; o += 512;
    const size_t P_CXP   = o; o += 147456;
    const size_t P_CDTW  = o; o += 16384;
    const size_t P_CDTB  = o; o += 512;
    const size_t P_CAL   = o; o += 65536;
    const size_t P_CD    = o; o += 512;
    const size_t P_COW   = o; o += 262144;
    const size_t OFF_FLAG = o;               // 1 int

    int* flagp = (int*)(ws + OFF_FLAG);

    // 0) detect input dtype
    detect_kernel<<<1, 256, 0, stream>>>((const unsigned short*)d_in[idx[0]], flagp);

    // 1) widen all 25 inputs to f32
    WDT tab;
    const int ns[25] = {2097152, 524288, 512, 1024, 1024, 2048, 2,
                        524288, 2048, 512, 147456, 16384, 512, 65536, 512, 262144,
                        1048576, 2048, 512, 147456, 16384, 512, 65536, 512, 262144};
    float* dsts[25] = {
        ws + A0, ws + P_FEATW, ws + P_FEATB, ws + P_CLS1, ws + P_CLS2,
        ws + P_CLSW, ws + P_CLSB,
        ws + P_MINW, ws + P_MCW, ws + P_MCB, ws + P_MXP, ws + P_MDTW, ws + P_MDTB,
        ws + P_MAL, ws + P_MD, ws + P_MOW,
        ws + P_CINW, ws + P_CCW, ws + P_CCB, ws + P_CXP, ws + P_CDTW, ws + P_CDTB,
        ws + P_CAL, ws + P_CD, ws + P_COW};
    for (int i = 0; i < 25; ++i) {
        tab.e[i].src = d_in[idx[i]];
        tab.e[i].dst = dsts[i];
        tab.e[i].n = ns[i];
    }
    widen_all_kernel<<<dim3(128, 25), 256, 0, stream>>>(tab, flagp);

    // 2) f = relu(x @ feat_w + feat_b)        A -> B
    gemm_mfma_kernel<<<dim3(32, 8, 1), 256, 0, stream>>>(ws + A0, 1024, 0, ws + P_FEATW, 512,
                                                         ws + P_FEATB, ws + B0, 512, 0,
                                                         2048, 1024, 1);
    // 3) xz = f @ m_in_w                      B -> C
    gemm_mfma_kernel<<<dim3(32, 16, 1), 256, 0, stream>>>(ws + B0, 512, 0, ws + P_MINW, 1024,
                                                          nullptr, ws + C0, 1024, 0,
                                                          2048, 512, 0);
    // 4) conv+silu, both directions           C -> D
    conv_silu_kernel<<<8192, 256, 0, stream>>>(ws + C0, 1024, 0, ws + P_MCW, ws + P_MCB,
                                               ws + D0, 2048, 1);
    // 5) x_dbl = xs @ m_xproj_w               D -> E
    gemm_mfma_kernel<<<dim3(32, 5, 2), 256, 0, stream>>>(ws + D0, 512, 2048LL * 512, ws + P_MXP,
                                                         288, nullptr, ws + E0, 288, 2048LL * 288,
                                                         2048, 512, 0);
    // 5b) dt = softplus(x_dbl[:, :32] @ dt_w + dt_b)   E -> DT_S (A)
    dt_kernel<<<8192, 256, 0, stream>>>(ws + E0, ws + P_MDTW, ws + P_MDTB, ws + DT_S, 2048);
    // 6) chunked scan: T=2048, 16 chunks x 128
    scan_part1_kernel<<<16384, 64, 0, stream>>>(ws + DT_S, ws + E0, ws + D0, ws + P_MAL,
                                                ws + P_S, ws + H_S, 2048, 16, 128);
    scan_combine_kernel<<<1024, 128, 0, stream>>>(ws + P_S, ws + H_S, nullptr, 16);
    scan_emit_kernel<<<16384, 64, 0, stream>>>(ws + DT_S, ws + E0, ws + D0, ws + P_MAL,
                                               ws + P_S, ws + F0, ws + H_S, 2048, 16, 128);
    // 6b) gate: y = (y0+y1 + xs*D)*silu(z)    F,H_S,D,C -> F
    gate_kernel<<<8192, 256, 0, stream>>>(ws + F0, ws + H_S, ws + D0, ws + C0, ws + P_MD, 2048);
    // 7) yo = y @ m_out_w                     F -> A (yo)
    gemm_mfma_kernel<<<dim3(32, 8, 2), 256, 0, stream>>>(ws + F0, 512, 2048LL * 512, ws + P_MOW,
                                                         512, nullptr, ws + A0, 512, 2048LL * 512,
                                                         2048, 512, 0);
    // 8) cls-token rows into SEQ              P -> G
    cls_rows_kernel<<<8, 256, 0, stream>>>(ws + P_CLS1, ws + P_CLS2, ws + G0);
    // 9) softmax + scatter                    A -> G
    softmax_scatter_kernel<<<dim3(2048, 2), 256, 0, stream>>>(ws + A0, ws + G0, 2048);
    // 10) cross in-proj                       G -> C (XZC spans C,D,+head of E)
    gemm_mfma_kernel<<<dim3(33, 16, 2), 256, 0, stream>>>(ws + G0, 1024, 2049LL * 1024, ws + P_CINW,
                                                          1024, nullptr, ws + C0, 1024,
                                                          2049LL * 1024, 2049, 1024, 0);
    // 11) cross conv+silu                     C -> A (XSC)
    conv_silu_kernel<<<8196, 256, 0, stream>>>(ws + C0, 1024, 2049LL * 1024, ws + P_CCW,
                                               ws + P_CCB, ws + A0, 2049, 0);
    // 12) cross x_dbl                         A -> B (XDC)
    gemm_mfma_kernel<<<dim3(33, 5, 2), 256, 0, stream>>>(ws + A0, 512, 2049LL * 512, ws + P_CXP,
                                                         288, nullptr, ws + B0, 288, 2049LL * 288,
                                                         2049, 512, 0);
    // 12b) cross dt                           B -> DT_C
    dt_kernel<<<8196, 256, 0, stream>>>(ws + B0, ws + P_CDTW, ws + P_CDTB, ws + DT_C, 2049);
    // 13) cross chunked scan: T=2049, 17 chunks x 128
    scan_part1_kernel<<<17408, 64, 0, stream>>>(ws + DT_C, ws + B0, ws + A0, ws + P_CAL,
                                                ws + P_C, ws + H_C, 2049, 17, 128);
    scan_combine_kernel<<<1024, 128, 0, stream>>>(ws + P_C, ws + H_C, ws + HFIN, 17);
    cross_readout_kernel<<<1024, 64, 0, stream>>>(ws + HFIN, ws + B0, ws + A0, ws + C0,
                                                  ws + P_CD, ws + YL0, 2049);
    // 14) out-projection of last rows         YL -> OL
    vecmat_kernel<<<dim3(2, 2), 256, 0, stream>>>(ws + YL0, ws + P_COW, ws + OL0);
    // 15) classifier                          OL -> out (f32)
    final_kernel<<<1, 256, 0, stream>>>(ws + OL0, ws + P_CLSW, ws + P_CLSB, out);
}

// Round 9
// 724.250 us; speedup vs baseline: 7.2931x; 1.0965x over previous
//
#include <hip/hip_runtime.h>
#include <hip/hip_bf16.h>

#define TC    2049
#define DI    512
#define NS    128
#define XPN   288   // DT_RANK + 2*N_STATE = 32 + 256

typedef short bfx8 __attribute__((ext_vector_type(8)));
typedef float f32x4 __attribute__((ext_vector_type(4)));

__device__ __forceinline__ float us2f(unsigned short u) {
    union { unsigned int i; float f; } v; v.i = ((unsigned int)u) << 16; return v.f;
}
__device__ __forceinline__ unsigned short f2bf(float f) {
    unsigned int u = __float_as_uint(f);
    u = (u + 0x7FFF + ((u >> 16) & 1)) >> 16;   // round-to-nearest-even
    return (unsigned short)u;
}
__device__ __forceinline__ float sigm(float x) { return 1.f / (1.f + __expf(-x)); }

#define L2E 1.4426950408889634f

// ---------------- dtype sniffing: bf16 inputs (flag=0) vs f32 inputs (flag=1) -----
__global__ void detect_kernel(const unsigned short* __restrict__ x, int* __restrict__ flag) {
    __shared__ int cnt;
    int tid = threadIdx.x;
    if (tid == 0) cnt = 0;
    __syncthreads();
    unsigned short u = x[tid];
    int e = (u >> 7) & 0xFF;
    int insane = (u != 0 && (e < 97 || e > 157)) ? 1 : 0;
    atomicAdd(&cnt, insane);
    __syncthreads();
    if (tid == 0) *flag = (cnt >= 64) ? 1 : 0;
}

// ---------------- widen all inputs to f32 in workspace ----------------
struct WD { const void* src; float* dst; int n; };
struct WDT { WD e[25]; };
__global__ __launch_bounds__(256) void widen_all_kernel(WDT tab, const int* __restrict__ flag) {
    WD d = tab.e[blockIdx.y];
    const int f = *flag;
    const int stride = gridDim.x * 256;
    int i = blockIdx.x * 256 + threadIdx.x;
    if (f) {
        const float* s = (const float*)d.src;
        for (; i < d.n; i += stride) d.dst[i] = s[i];
    } else {
        const unsigned short* s = (const unsigned short*)d.src;
        for (; i < d.n; i += stride) d.dst[i] = us2f(s[i]);
    }
}

// ---------------- bf16-MFMA GEMM (f32 in/out, bf16 matrix cores) ------------------
__global__ __launch_bounds__(256) void gemm_mfma_kernel(
    const float* __restrict__ A, int lda, long long sA,
    const float* __restrict__ W, int N,
    const float* __restrict__ bias,
    float* __restrict__ C, int ldc, long long sC,
    int M, int K, int act)
{
    A += (size_t)blockIdx.z * sA;
    C += (size_t)blockIdx.z * sC;
    __shared__ __align__(16) unsigned short As[64][40];   // [m][k] bf16
    __shared__ __align__(16) unsigned short Bs[64][40];   // [n][k] bf16 (transposed)
    const int tid = threadIdx.x;
    const int wave = tid >> 6, lane = tid & 63;
    const int bm = blockIdx.x * 64, bn = blockIdx.y * 64;
    const int col = lane & 15, quad = lane >> 4;

    f32x4 acc[4] = {{0.f,0.f,0.f,0.f},{0.f,0.f,0.f,0.f},{0.f,0.f,0.f,0.f},{0.f,0.f,0.f,0.f}};

    const int ar = tid >> 2, ak = (tid & 3) << 3;        // A: row 0..63, k-chunk of 8
    const int kr = tid >> 3, nb = (tid & 7) << 3;        // W: k-row 0..31, n-chunk of 8

    for (int kt = 0; kt < K; kt += 32) {
        float va[8];
        int gm = bm + ar;
        if (gm < M) {
            const float* ap = A + (size_t)gm * lda + kt + ak;
            float4 v0 = *(const float4*)ap;
            float4 v1 = *(const float4*)(ap + 4);
            va[0]=v0.x; va[1]=v0.y; va[2]=v0.z; va[3]=v0.w;
            va[4]=v1.x; va[5]=v1.y; va[6]=v1.z; va[7]=v1.w;
        } else {
#pragma unroll
            for (int j = 0; j < 8; ++j) va[j] = 0.f;
        }
        float vb[8];
        int gn0 = bn + nb;
        const float* wp = W + (size_t)(kt + kr) * N + gn0;
        if (gn0 + 7 < N) {
            float4 w0 = *(const float4*)wp;
            float4 w1 = *(const float4*)(wp + 4);
            vb[0]=w0.x; vb[1]=w0.y; vb[2]=w0.z; vb[3]=w0.w;
            vb[4]=w1.x; vb[5]=w1.y; vb[6]=w1.z; vb[7]=w1.w;
        } else {
#pragma unroll
            for (int j = 0; j < 8; ++j) vb[j] = (gn0 + j < N) ? wp[j] : 0.f;
        }
        __syncthreads();
        bfx8 apk;
#pragma unroll
        for (int j = 0; j < 8; ++j) apk[j] = (short)f2bf(va[j]);
        *(bfx8*)&As[ar][ak] = apk;
#pragma unroll
        for (int j = 0; j < 8; ++j) Bs[nb + j][kr] = f2bf(vb[j]);
        __syncthreads();
        bfx8 af = *(const bfx8*)&As[wave * 16 + col][quad << 3];
#pragma unroll
        for (int ct = 0; ct < 4; ++ct) {
            bfx8 bf = *(const bfx8*)&Bs[ct * 16 + col][quad << 3];
            acc[ct] = __builtin_amdgcn_mfma_f32_16x16x32_bf16(af, bf, acc[ct], 0, 0, 0);
        }
    }
#pragma unroll
    for (int ct = 0; ct < 4; ++ct) {
        int gn = bn + ct * 16 + col;
        if (gn >= N) continue;
        float bv = bias ? bias[gn] : 0.f;
#pragma unroll
        for (int r = 0; r < 4; ++r) {
            int gm = bm + wave * 16 + quad * 4 + r;
            if (gm < M) {
                float v = acc[ct][r] + bv;
                if (act == 1) v = fmaxf(v, 0.f);
                C[(size_t)gm * ldc + gn] = v;
            }
        }
    }
}

// ---------------- causal depthwise conv (K=4) + silu, batched 2 dirs ----------------
__global__ __launch_bounds__(256) void conv_silu_kernel(
    const float* __restrict__ xzbase, int ld, long long bstride,
    const float* __restrict__ conv_w, const float* __restrict__ conv_b,
    float* __restrict__ xs, int T, int rev_mode)
{
    int idx = blockIdx.x * 256 + threadIdx.x;
    if (idx >= 2 * T * DI) return;
    int half = idx / (T * DI);
    int rem = idx - half * T * DI;
    int t = rem >> 9, d = rem & 511;
    const float* xzp = xzbase + (rev_mode ? 0 : (size_t)half * bstride);
    int rev = rev_mode ? half : 0;
    float acc = conv_b[d];
#pragma unroll
    for (int k = 0; k < 4; ++k) {
        int tt = t - 3 + k;
        if (tt >= 0) {
            int g = rev ? (T - 1 - tt) : tt;
            acc += conv_w[d * 4 + k] * xzp[(size_t)g * ld + d];
        }
    }
    xs[idx] = acc * sigm(acc);
}

// ---------------- dt projection (K=32) + softplus ----------------
__global__ __launch_bounds__(256) void dt_kernel(
    const float* __restrict__ xdbl, const float* __restrict__ dt_w,
    const float* __restrict__ dt_b, float* __restrict__ dtout, int T)
{
    int idx = blockIdx.x * 256 + threadIdx.x;
    if (idx >= 2 * T * DI) return;
    int half = idx / (T * DI);
    int rem = idx - half * T * DI;
    int t = rem >> 9, j = rem & 511;
    const float* a = xdbl + (size_t)half * T * XPN + (size_t)t * XPN;
    float acc = dt_b[j];
#pragma unroll
    for (int k = 0; k < 32; ++k) acc += a[k] * dt_w[k * DI + j];
    dtout[idx] = (acc > 20.f) ? acc : log1pf(__expf(acc));
}

// ---------------- chunked scan pass 1 (2 d's per wave, 4 states/lane) ----------------
// blockIdx.x = dpair*NC + c ; lanes 0-31 -> d0, lanes 32-63 -> d1=d0+1
__global__ __launch_bounds__(64) void scan_part1_kernel(
    const float* __restrict__ dt, const float* __restrict__ xdbl,
    const float* __restrict__ xs, const float* __restrict__ A_log,
    float* __restrict__ P, float* __restrict__ H, int T, int NC, int LC)
{
    int b = blockIdx.x;
    int c = b % NC;
    int dp = b / NC;
    int hd0 = dp * 2;
    int half = hd0 >> 9;
    int lane = threadIdx.x;
    int g = lane >> 5, l = lane & 31;
    int hd = hd0 + g;
    int d = hd & 511;
    const float a0 = -__expf(A_log[d * NS + l])      * L2E;
    const float a1 = -__expf(A_log[d * NS + 32 + l]) * L2E;
    const float a2 = -__expf(A_log[d * NS + 64 + l]) * L2E;
    const float a3 = -__expf(A_log[d * NS + 96 + l]) * L2E;
    int t0 = c * LC, t1 = min(T, t0 + LC);
    const float* dtp = dt + (size_t)half * T * DI + (size_t)t0 * DI + d;
    const float* xsp = xs + (size_t)half * T * DI + (size_t)t0 * DI + d;
    const float* row = xdbl + (size_t)half * T * XPN + (size_t)t0 * XPN;
    float P0 = 1.f, P1 = 1.f, P2 = 1.f, P3 = 1.f;
    float h0 = 0.f, h1 = 0.f, h2 = 0.f, h3 = 0.f;
    for (int t = t0; t < t1; ++t) {
        float dv = *dtp, xv = *xsp;
        float B0 = row[32 + l], B1 = row[64 + l], B2 = row[96 + l], B3 = row[128 + l];
        float e0 = exp2f(dv * a0), e1 = exp2f(dv * a1);
        float e2 = exp2f(dv * a2), e3 = exp2f(dv * a3);
        float u = dv * xv;
        h0 = h0 * e0 + u * B0;  h1 = h1 * e1 + u * B1;
        h2 = h2 * e2 + u * B2;  h3 = h3 * e3 + u * B3;
        P0 *= e0; P1 *= e1; P2 *= e2; P3 *= e3;
        dtp += DI; xsp += DI; row += XPN;
    }
    size_t base = ((size_t)hd * NC + c) * 128 + l;
    P[base] = P0; P[base + 32] = P1; P[base + 64] = P2; P[base + 96] = P3;
    H[base] = h0; H[base + 32] = h1; H[base + 64] = h2; H[base + 96] = h3;
}

// ---------------- chunked scan pass 2: serial combine across chunks ----------------
__global__ __launch_bounds__(128) void scan_combine_kernel(
    float* __restrict__ P, const float* __restrict__ H,
    float* __restrict__ Hfinal, int NC)
{
    int hd = blockIdx.x;
    int n = threadIdx.x;
    size_t base = (size_t)hd * NC * 128 + n;
    float h = 0.f;
    for (int c = 0; c < NC; ++c) {
        size_t off = base + (size_t)c * 128;
        float p = P[off];
        float hh = H[off];
        P[off] = h;                // h_start for chunk c (exclusive prefix)
        h = p * h + hh;
    }
    if (Hfinal) Hfinal[(size_t)hd * 128 + n] = h;
}

// ---------------- chunked scan pass 3: replay with seed, emit full y ----------------
// 2 d's per wave; 5 xor-shuffles inside each 32-lane group give COMPLETE sums.
__global__ __launch_bounds__(64) void scan_emit_kernel(
    const float* __restrict__ dt, const float* __restrict__ xdbl,
    const float* __restrict__ xs, const float* __restrict__ A_log,
    const float* __restrict__ Hstart,
    float* __restrict__ y, int T, int NC, int LC)
{
    int b = blockIdx.x;
    int c = b % NC;
    int dp = b / NC;
    int hd0 = dp * 2;
    int half = hd0 >> 9;
    int lane = threadIdx.x;
    int g = lane >> 5, l = lane & 31;
    int hd = hd0 + g;
    int d = hd & 511;
    const float a0 = -__expf(A_log[d * NS + l])      * L2E;
    const float a1 = -__expf(A_log[d * NS + 32 + l]) * L2E;
    const float a2 = -__expf(A_log[d * NS + 64 + l]) * L2E;
    const float a3 = -__expf(A_log[d * NS + 96 + l]) * L2E;
    size_t base = ((size_t)hd * NC + c) * 128 + l;
    float h0 = Hstart[base];
    float h1 = Hstart[base + 32];
    float h2 = Hstart[base + 64];
    float h3 = Hstart[base + 96];
    int t0 = c * LC, t1 = min(T, t0 + LC);
    const float* dtp = dt + (size_t)half * T * DI + (size_t)t0 * DI + d;
    const float* xsp = xs + (size_t)half * T * DI + (size_t)t0 * DI + d;
    const float* row = xdbl + (size_t)half * T * XPN + (size_t)t0 * XPN;
    float* yp = y + (size_t)half * T * DI + (size_t)t0 * DI + d;
    for (int t = t0; t < t1; ++t) {
        float dv = *dtp, xv = *xsp;
        float B0 = row[32 + l],  B1 = row[64 + l],  B2 = row[96 + l],  B3 = row[128 + l];
        float C0 = row[160 + l], C1 = row[192 + l], C2 = row[224 + l], C3 = row[256 + l];
        float e0 = exp2f(dv * a0), e1 = exp2f(dv * a1);
        float e2 = exp2f(dv * a2), e3 = exp2f(dv * a3);
        float u = dv * xv;
        h0 = h0 * e0 + u * B0;  h1 = h1 * e1 + u * B1;
        h2 = h2 * e2 + u * B2;  h3 = h3 * e3 + u * B3;
        float p = h0 * C0 + h1 * C1 + h2 * C2 + h3 * C3;
        p += __shfl_xor(p, 1, 64);
        p += __shfl_xor(p, 2, 64);
        p += __shfl_xor(p, 4, 64);
        p += __shfl_xor(p, 8, 64);
        p += __shfl_xor(p, 16, 64);
        if (l == 0) *yp = p;
        dtp += DI; xsp += DI; row += XPN; yp += DI;
    }
}

// ---------------- gate: y = (y + xs*D) * silu(z[flip]) ----------------
__global__ __launch_bounds__(256) void gate_kernel(
    float* __restrict__ y, const float* __restrict__ xs,
    const float* __restrict__ xz, const float* __restrict__ Dp, int T)
{
    int idx = blockIdx.x * 256 + threadIdx.x;
    if (idx >= 2 * T * DI) return;
    int half = idx / (T * DI);
    int rem = idx - half * T * DI;
    int t = rem >> 9, d = rem & 511;
    int tg = half ? (T - 1 - t) : t;
    float z = xz[(size_t)tg * 1024 + 512 + d];
    float p = y[idx] + xs[idx] * Dp[d];
    y[idx] = p * (z * sigm(z));
}

// ---------------- cross: last-step readout from final state + gating ----------------
__global__ __launch_bounds__(64) void cross_readout_kernel(
    const float* __restrict__ Hfinal, const float* __restrict__ xdbl,
    const float* __restrict__ xs, const float* __restrict__ xz,
    const float* __restrict__ Dp, float* __restrict__ ylast, int T)
{
    int hd = blockIdx.x;
    int half = hd >> 9, d = hd & 511;
    int lane = threadIdx.x;
    xdbl += (size_t)half * T * XPN;
    xs   += (size_t)half * T * DI;
    xz   += (size_t)half * T * 1024;
    float h0 = Hfinal[(size_t)hd * 128 + lane];
    float h1 = Hfinal[(size_t)hd * 128 + 64 + lane];
    const float* xl = xdbl + (size_t)(T - 1) * XPN;
    float p = h0 * xl[160 + lane] + h1 * xl[224 + lane];
#pragma unroll
    for (int off = 32; off > 0; off >>= 1) p += __shfl_down(p, off, 64);
    if (lane == 0) {
        float xlast = xs[(size_t)(T - 1) * DI + d];
        float zl = xz[(size_t)(T - 1) * 1024 + 512 + d];
        ylast[half * DI + d] = (p + xlast * Dp[d]) * (zl * sigm(zl));
    }
}

// ---------------- row softmax + scatter into both cross sequences ----------------
__global__ __launch_bounds__(256) void softmax_scatter_kernel(
    const float* __restrict__ yo, float* __restrict__ seq, int T)
{
    __shared__ float sm[4];
    const int t = blockIdx.x, half = blockIdx.y, tid = threadIdx.x;
    const float* row = yo + (size_t)half * T * DI + (size_t)t * DI;
    float v0 = row[tid], v1 = row[tid + 256];
    float m = fmaxf(v0, v1);
#pragma unroll
    for (int o = 32; o > 0; o >>= 1) m = fmaxf(m, __shfl_xor(m, o, 64));
    if ((tid & 63) == 0) sm[tid >> 6] = m;
    __syncthreads();
    m = fmaxf(fmaxf(sm[0], sm[1]), fmaxf(sm[2], sm[3]));
    __syncthreads();
    float e0 = __expf(v0 - m), e1 = __expf(v1 - m);
    float s = e0 + e1;
#pragma unroll
    for (int o = 32; o > 0; o >>= 1) s += __shfl_xor(s, o, 64);
    if ((tid & 63) == 0) sm[tid >> 6] = s;
    __syncthreads();
    s = sm[0] + sm[1] + sm[2] + sm[3];
    float inv = 1.f / s;
    e0 *= inv; e1 *= inv;
    float* seq_fi = seq;
    float* seq_if = seq + (size_t)TC * 1024;
    if (half == 0) {
        float* d1 = seq_fi + (size_t)t * 1024;
        float* d2 = seq_if + (size_t)t * 1024 + 512;
        d1[tid] = e0; d1[tid + 256] = e1;
        d2[tid] = e0; d2[tid + 256] = e1;
    } else {
        int tg = T - 1 - t;
        float* d1 = seq_fi + (size_t)tg * 1024 + 512;
        float* d2 = seq_if + (size_t)tg * 1024;
        d1[tid] = e0; d1[tid + 256] = e1;
        d2[tid] = e0; d2[tid + 256] = e1;
    }
}

// ---------------- cls-token rows of the two sequences ----------------
__global__ __launch_bounds__(256) void cls_rows_kernel(
    const float* __restrict__ cls1, const float* __restrict__ cls2,
    float* __restrict__ seq)
{
    int i = blockIdx.x * 256 + threadIdx.x;   // 0..2047
    if (i < 1024)
        seq[(size_t)(TC - 1) * 1024 + i] = cls1[i];
    else
        seq[(size_t)TC * 1024 + (size_t)(TC - 1) * 1024 + (i - 1024)] = cls2[i - 1024];
}

// ---------------- vec [512] @ out_w [512,512] -> [512] ----------------
__global__ __launch_bounds__(256) void vecmat_kernel(
    const float* __restrict__ ylast, const float* __restrict__ Wout,
    float* __restrict__ olast)
{
    int half = blockIdx.y;
    int j = blockIdx.x * 256 + threadIdx.x;
    const float* v = ylast + half * DI;
    float acc = 0.f;
    for (int k = 0; k < DI; ++k) acc += v[k] * Wout[k * DI + j];
    olast[half * DI + j] = acc;
}

// ---------------- final classifier -> f32 [2] ----------------
__global__ __launch_bounds__(256) void final_kernel(
    const float* __restrict__ ol, const float* __restrict__ cw,
    const float* __restrict__ cb, float* __restrict__ out)
{
    __shared__ float s0[4], s1[4];
    int tid = threadIdx.x;
    float a0 = 0.f, a1 = 0.f;
    for (int j = tid; j < 1024; j += 256) {
        float v = ol[j];
        a0 += v * cw[2 * j];
        a1 += v * cw[2 * j + 1];
    }
#pragma unroll
    for (int o = 32; o > 0; o >>= 1) { a0 += __shfl_xor(a0, o, 64); a1 += __shfl_xor(a1, o, 64); }
    if ((tid & 63) == 0) { s0[tid >> 6] = a0; s1[tid >> 6] = a1; }
    __syncthreads();
    if (tid == 0) {
        out[0] = s0[0] + s0[1] + s0[2] + s0[3] + cb[0];
        out[1] = s1[0] + s1[1] + s1[2] + s1[3] + cb[1];
    }
}

extern "C" void kernel_launch(void* const* d_in, const int* in_sizes, int n_in,
                              void* d_out, int out_size, void* d_ws, size_t ws_size,
                              hipStream_t stream)
{
    float* out = (float*)d_out;
    float* ws = (float*)d_ws;

    // ---- input-order resolution via in_sizes (dict vs signature order) ----
    static const int sig_map[25] = {0,1,2,3,4,23,24,5,6,7,8,9,10,11,12,13,
                                    14,15,16,17,18,19,20,21,22};
    int idx[25];
    bool dict_order = (n_in >= 7 && in_sizes[6] == 2);
    for (int i = 0; i < 25; ++i) idx[i] = dict_order ? i : sig_map[i];

    // ---- aliased workspace layout (f32 elements) ----
    const size_t A0 = 0;         // x(f32) -> dt_simple -> yo -> XSC          (2,098,176)
    const size_t B0 = 2098176;   // f -> XDC                                  (1,180,224)
    const size_t C0 = 3278400;   // XZS / XZC (XZC spans ..7,474,752)         (2,097,152)
    const size_t D0 = 5375552;   // XS                                        (2,097,152)
    const size_t E0 = 7472704;   // XDBL                                      (1,179,648)
    const size_t F0 = 8652352;   // y / YS                                    (2,097,152)
    const size_t G0 = 10749504;  // P_S | H_S  -> SEQ                         (4,196,352)
    const size_t YL0 = 14945856; // 1024
    const size_t OL0 = 14946880; // 1024
    const size_t DT_S = A0;
    const size_t P_S  = G0;
    const size_t H_S  = G0 + 2097152;
    const size_t DT_C = 7474752;
    const size_t P_C  = 9572928;
    const size_t H_C  = 11801152;
    const size_t HFIN = 14029376;
    size_t o = 14947904;
    const size_t P_FEATW = o; o += 524288;
    const size_t P_FEATB = o; o += 512;
    const size_t P_CLS1  = o; o += 1024;
    const size_t P_CLS2  = o; o += 1024;
    const size_t P_CLSW  = o; o += 2048;
    const size_t P_CLSB  = o; o += 4;
    const size_t P_MINW  = o; o += 524288;
    const size_t P_MCW   = o; o += 2048;
    const size_t P_MCB   = o; o += 512;
    const size_t P_MXP   = o; o += 147456;
    const size_t P_MDTW  = o; o += 16384;
    const size_t P_MDTB  = o; o += 512;
    const size_t P_MAL   = o; o += 65536;
    const size_t P_MD    = o; o += 512;
    const size_t P_MOW   = o; o += 262144;
    const size_t P_CINW  = o; o += 1048576;
    const size_t P_CCW   = o; o += 2048;
    const size_t P_CCB   = o; o += 512;
    const size_t P_CXP   = o; o += 147456;
    const size_t P_CDTW  = o; o += 16384;
    const size_t P_CDTB  = o; o += 512;
    const size_t P_CAL   = o; o += 65536;
    const size_t P_CD    = o; o += 512;
    const size_t P_COW   = o; o += 262144;
    const size_t OFF_FLAG = o;               // 1 int

    int* flagp = (int*)(ws + OFF_FLAG);

    // 0) detect input dtype
    detect_kernel<<<1, 256, 0, stream>>>((const unsigned short*)d_in[idx[0]], flagp);

    // 1) widen all 25 inputs to f32
    WDT tab;
    const int ns[25] = {2097152, 524288, 512, 1024, 1024, 2048, 2,
                        524288, 2048, 512, 147456, 16384, 512, 65536, 512, 262144,
                        1048576, 2048, 512, 147456, 16384, 512, 65536, 512, 262144};
    float* dsts[25] = {
        ws + A0, ws + P_FEATW, ws + P_FEATB, ws + P_CLS1, ws + P_CLS2,
        ws + P_CLSW, ws + P_CLSB,
        ws + P_MINW, ws + P_MCW, ws + P_MCB, ws + P_MXP, ws + P_MDTW, ws + P_MDTB,
        ws + P_MAL, ws + P_MD, ws + P_MOW,
        ws + P_CINW, ws + P_CCW, ws + P_CCB, ws + P_CXP, ws + P_CDTW, ws + P_CDTB,
        ws + P_CAL, ws + P_CD, ws + P_COW};
    for (int i = 0; i < 25; ++i) {
        tab.e[i].src = d_in[idx[i]];
        tab.e[i].dst = dsts[i];
        tab.e[i].n = ns[i];
    }
    widen_all_kernel<<<dim3(128, 25), 256, 0, stream>>>(tab, flagp);

    // 2) f = relu(x @ feat_w + feat_b)        A -> B
    gemm_mfma_kernel<<<dim3(32, 8, 1), 256, 0, stream>>>(ws + A0, 1024, 0, ws + P_FEATW, 512,
                                                         ws + P_FEATB, ws + B0, 512, 0,
                                                         2048, 1024, 1);
    // 3) xz = f @ m_in_w                      B -> C
    gemm_mfma_kernel<<<dim3(32, 16, 1), 256, 0, stream>>>(ws + B0, 512, 0, ws + P_MINW, 1024,
                                                          nullptr, ws + C0, 1024, 0,
                                                          2048, 512, 0);
    // 4) conv+silu, both directions           C -> D
    conv_silu_kernel<<<8192, 256, 0, stream>>>(ws + C0, 1024, 0, ws + P_MCW, ws + P_MCB,
                                               ws + D0, 2048, 1);
    // 5) x_dbl = xs @ m_xproj_w               D -> E
    gemm_mfma_kernel<<<dim3(32, 5, 2), 256, 0, stream>>>(ws + D0, 512, 2048LL * 512, ws + P_MXP,
                                                         288, nullptr, ws + E0, 288, 2048LL * 288,
                                                         2048, 512, 0);
    // 5b) dt = softplus(x_dbl[:, :32] @ dt_w + dt_b)   E -> DT_S (A)
    dt_kernel<<<8192, 256, 0, stream>>>(ws + E0, ws + P_MDTW, ws + P_MDTB, ws + DT_S, 2048);
    // 6) chunked scan: T=2048, 16 chunks x 128, 2 d's/wave
    scan_part1_kernel<<<8192, 64, 0, stream>>>(ws + DT_S, ws + E0, ws + D0, ws + P_MAL,
                                               ws + P_S, ws + H_S, 2048, 16, 128);
    scan_combine_kernel<<<1024, 128, 0, stream>>>(ws + P_S, ws + H_S, nullptr, 16);
    scan_emit_kernel<<<8192, 64, 0, stream>>>(ws + DT_S, ws + E0, ws + D0, ws + P_MAL,
                                              ws + P_S, ws + F0, 2048, 16, 128);
    // 6b) gate: y = (y + xs*D)*silu(z)        F,D,C -> F
    gate_kernel<<<8192, 256, 0, stream>>>(ws + F0, ws + D0, ws + C0, ws + P_MD, 2048);
    // 7) yo = y @ m_out_w                     F -> A (yo)
    gemm_mfma_kernel<<<dim3(32, 8, 2), 256, 0, stream>>>(ws + F0, 512, 2048LL * 512, ws + P_MOW,
                                                         512, nullptr, ws + A0, 512, 2048LL * 512,
                                                         2048, 512, 0);
    // 8) cls-token rows into SEQ              P -> G
    cls_rows_kernel<<<8, 256, 0, stream>>>(ws + P_CLS1, ws + P_CLS2, ws + G0);
    // 9) softmax + scatter                    A -> G
    softmax_scatter_kernel<<<dim3(2048, 2), 256, 0, stream>>>(ws + A0, ws + G0, 2048);
    // 10) cross in-proj                       G -> C (XZC spans C,D,+head of E)
    gemm_mfma_kernel<<<dim3(33, 16, 2), 256, 0, stream>>>(ws + G0, 1024, 2049LL * 1024, ws + P_CINW,
                                                          1024, nullptr, ws + C0, 1024,
                                                          2049LL * 1024, 2049, 1024, 0);
    // 11) cross conv+silu                     C -> A (XSC)
    conv_silu_kernel<<<8196, 256, 0, stream>>>(ws + C0, 1024, 2049LL * 1024, ws + P_CCW,
                                               ws + P_CCB, ws + A0, 2049, 0);
    // 12) cross x_dbl                         A -> B (XDC)
    gemm_mfma_kernel<<<dim3(33, 5, 2), 256, 0, stream>>>(ws + A0, 512, 2049LL * 512, ws + P_CXP,
                                                         288, nullptr, ws + B0, 288, 2049LL * 288,
                                                         2049, 512, 0);
    // 12b) cross dt                           B -> DT_C
    dt_kernel<<<8196, 256, 0, stream>>>(ws + B0, ws + P_CDTW, ws + P_CDTB, ws + DT_C, 2049);
    // 13) cross chunked scan: T=2049, 17 chunks x 128, 2 d's/wave
    scan_part1_kernel<<<8704, 64, 0, stream>>>(ws + DT_C, ws + B0, ws + A0, ws + P_CAL,
                                               ws + P_C, ws + H_C, 2049, 17, 128);
    scan_combine_kernel<<<1024, 128, 0, stream>>>(ws + P_C, ws + H_C, ws + HFIN, 17);
    cross_readout_kernel<<<1024, 64, 0, stream>>>(ws + HFIN, ws + B0, ws + A0, ws + C0,
                                                  ws + P_CD, ws + YL0, 2049);
    // 14) out-projection of last rows         YL -> OL
    vecmat_kernel<<<dim3(2, 2), 256, 0, stream>>>(ws + YL0, ws + P_COW, ws + OL0);
    // 15) classifier                          OL -> out (f32)
    final_kernel<<<1, 256, 0, stream>>>(ws + OL0, ws + P_CLSW, ws + P_CLSB, out);
}